// Round 1
// baseline (1563.385 us; speedup 1.0000x reference)
//
#include <hip/hip_runtime.h>
#include <cmath>

// Problem constants
constexpr int Bb = 8, Hh = 8, Dd = 512, DHd = 64, Ll = 1024;

struct BTab { int nb; float bnd[64]; float prior[25]; };

__device__ __forceinline__ float silu_f(float v) { return v / (1.f + expf(-v)); }

// ---------------------------------------------------------------------------
// Kernel 1: per-position feature MLPs, gates, rope-lambda, x update
// ---------------------------------------------------------------------------
__global__ __launch_bounds__(256) void k_pre(
    const float* __restrict__ x, const int* __restrict__ type_seq, const int* __restrict__ seq_time,
    const float* __restrict__ emb,
    const float* __restrict__ gW1, const float* __restrict__ gb1,
    const float* __restrict__ gW2, const float* __restrict__ gb2,
    const float* __restrict__ fW1, const float* __restrict__ fb1,
    const float* __restrict__ fW2, const float* __restrict__ fb2,
    const float* __restrict__ bW1, const float* __restrict__ bb1,
    const float* __restrict__ bW2, const float* __restrict__ bb2,
    const float* __restrict__ lW1, const float* __restrict__ lb1,
    const float* __restrict__ lW2, const float* __restrict__ lb2,
    float* __restrict__ x_new, float* __restrict__ qg, float* __restrict__ kg,
    float* __restrict__ vg, float* __restrict__ rl)
{
  int p = blockIdx.x;              // b*L + l
  int l = p & (Ll - 1);
  int t = threadIdx.x;
  __shared__ float feat[17];
  __shared__ float hbuf[6][32];    // 0..2 qkv gates, 3 fusion, 4 bproj, 5 lam
  int ty = type_seq[p];
  float mf = (ty != 0) ? 1.f : 0.f;
  if (t < 16) {
    feat[t] = emb[ty * 16 + t];
  } else if (t == 16) {
    float dtf = 0.f;
    if (l > 0) { int dd = seq_time[p] - seq_time[p - 1]; if (dd < 0) dd = 0; dtf = (float)dd; }
    feat[16] = log1pf(dtf * mf);
  }
  __syncthreads();
  if (t < 192) {
    int m = t >> 5, u = t & 31;
    const float *W1, *b1;
    switch (m) {
      case 0: case 1: case 2: W1 = gW1 + m * 544; b1 = gb1 + m * 32; break;
      case 3: W1 = fW1; b1 = fb1; break;
      case 4: W1 = bW1; b1 = bb1; break;
      default: W1 = lW1; b1 = lb1; break;
    }
    float a = b1[u];
    #pragma unroll
    for (int f = 0; f < 17; ++f) a += feat[f] * W1[f * 32 + u];
    hbuf[m][u] = silu_f(a);
  }
  __syncthreads();
  if (t < 24) {
    int g = t >> 3, hd = t & 7;
    float a = gb2[g * 8 + hd];
    #pragma unroll
    for (int u = 0; u < 32; ++u) a += hbuf[g][u] * gW2[g * 256 + u * 8 + hd];
    float val = tanhf(a);
    float coef = (g == 2) ? 0.25f : 0.12f;
    float gate = mf * (1.f + coef * val) + (1.f - mf);   // pad -> 1.0
    float* dst = (g == 0) ? qg : (g == 1) ? kg : vg;
    dst[p * 8 + hd] = gate;
  } else if (t == 24) {
    float a = lb2[0];
    #pragma unroll
    for (int u = 0; u < 32; ++u) a += hbuf[5][u] * lW2[u];
    rl[p] = (1.f + 0.15f * tanhf(a)) * mf;               // pad -> 0
  }
  // fusion / bproj outputs (512 each), x update
  #pragma unroll
  for (int r = 0; r < 2; ++r) {
    int dd = t + (r << 8);
    float af = fb2[dd], ab = bb2[dd];
    #pragma unroll
    for (int u = 0; u < 32; ++u) {
      af += hbuf[3][u] * fW2[u * 512 + dd];
      ab += hbuf[4][u] * bW2[u * 512 + dd];
    }
    float fg = 1.f / (1.f + expf(-af));
    x_new[(size_t)p * 512 + dd] = x[(size_t)p * 512 + dd] + fg * (ab * mf);
  }
}

// ---------------------------------------------------------------------------
// Kernel 2: inclusive cumsum of rope-lambda along L (per batch row)
// ---------------------------------------------------------------------------
__global__ __launch_bounds__(1024) void k_scan(const float* __restrict__ rl, float* __restrict__ pos)
{
  int b = blockIdx.x, t = threadIdx.x;
  __shared__ float buf[1024];
  buf[t] = rl[b * 1024 + t];
  __syncthreads();
  for (int off = 1; off < 1024; off <<= 1) {
    float add = (t >= off) ? buf[t - off] : 0.f;
    __syncthreads();
    buf[t] += add;
    __syncthreads();
  }
  pos[b * 1024 + t] = buf[t];
}

// ---------------------------------------------------------------------------
// Kernel 3/7: fp32 tiled GEMM  C[M=8192, N] = A[M,512] @ W[512,N]  (+epilogue)
// MODE 0: C = silu(acc + bias)      MODE 1: C = acc + bias + add[row,col]
// ---------------------------------------------------------------------------
template <int N, int MODE>
__global__ __launch_bounds__(256) void k_gemm(
    const float* __restrict__ A, const float* __restrict__ W,
    const float* __restrict__ bias, const float* __restrict__ add,
    float* __restrict__ C)
{
  __shared__ float As[16][68];
  __shared__ float Ws[16][68];
  int t = threadIdx.x;
  int row0 = blockIdx.y * 64;
  int col0 = blockIdx.x * 64;
  int ty = t >> 4, tx = t & 15;
  int lm = t >> 2, lk = (t & 3) << 2;    // A-tile load: row lm, k offset lk (float4)
  int wk = t >> 4, wn = (t & 15) << 2;   // W-tile load: k row wk, col offset wn (float4)
  float acc[4][4];
  #pragma unroll
  for (int i = 0; i < 4; ++i)
    #pragma unroll
    for (int j = 0; j < 4; ++j) acc[i][j] = 0.f;

  for (int k0 = 0; k0 < 512; k0 += 16) {
    float4 av = *reinterpret_cast<const float4*>(A + (size_t)(row0 + lm) * 512 + k0 + lk);
    float4 wv = *reinterpret_cast<const float4*>(W + (size_t)(k0 + wk) * N + col0 + wn);
    __syncthreads();
    As[lk + 0][lm] = av.x; As[lk + 1][lm] = av.y; As[lk + 2][lm] = av.z; As[lk + 3][lm] = av.w;
    *reinterpret_cast<float4*>(&Ws[wk][wn]) = wv;
    __syncthreads();
    #pragma unroll
    for (int kk = 0; kk < 16; ++kk) {
      float a[4], bb[4];
      *reinterpret_cast<float4*>(a)  = *reinterpret_cast<const float4*>(&As[kk][ty * 4]);
      *reinterpret_cast<float4*>(bb) = *reinterpret_cast<const float4*>(&Ws[kk][tx * 4]);
      #pragma unroll
      for (int i = 0; i < 4; ++i)
        #pragma unroll
        for (int j = 0; j < 4; ++j) acc[i][j] += a[i] * bb[j];
    }
  }
  #pragma unroll
  for (int i = 0; i < 4; ++i) {
    int row = row0 + ty * 4 + i;
    #pragma unroll
    for (int j = 0; j < 4; ++j) {
      int col = col0 + tx * 4 + j;
      float c = acc[i][j] + bias[col];
      if (MODE == 0) c = c / (1.f + expf(-c));
      else           c += add[(size_t)row * N + col];
      C[(size_t)row * N + col] = c;
    }
  }
}

// ---------------------------------------------------------------------------
// Kernel 4: RoPE + gates, transpose into (B*H, L, 64)
// ---------------------------------------------------------------------------
__global__ __launch_bounds__(256) void k_rope(
    const float* __restrict__ uvqk, const float* __restrict__ pos,
    const float* __restrict__ qg, const float* __restrict__ kg, const float* __restrict__ vg,
    float* __restrict__ q_r, float* __restrict__ k_r, float* __restrict__ v_r)
{
  int p = blockIdx.x;
  int b = p >> 10, l = p & 1023;
  int t = threadIdx.x;
  int hd = t >> 5, dp = t & 31;
  const float* base = uvqk + (size_t)p * 2048;
  float ps = pos[p];
  float infq = powf(10000.f, -((float)(2 * dp)) / 64.f);
  float ang = ps * infq;
  float c = cosf(ang), sn = sinf(ang);
  float qe = base[1024 + hd * 64 + 2 * dp], qo = base[1024 + hd * 64 + 2 * dp + 1];
  float ke = base[1536 + hd * 64 + 2 * dp], ko = base[1536 + hd * 64 + 2 * dp + 1];
  float gq = qg[p * 8 + hd], gk = kg[p * 8 + hd];
  size_t ob = ((size_t)(b * 8 + hd) * 1024 + l) * 64;
  q_r[ob + dp]      = (qe * c - qo * sn) * gq;
  q_r[ob + 32 + dp] = (qe * sn + qo * c) * gq;
  k_r[ob + dp]      = (ke * c - ko * sn) * gk;
  k_r[ob + 32 + dp] = (ke * sn + ko * c) * gk;
  #pragma unroll
  for (int r = 0; r < 2; ++r) {
    int dd = t + (r << 8);
    int hh = dd >> 6;
    v_r[((size_t)(b * 8 + hh) * 1024 + l) * 64 + (dd & 63)] = base[512 + dd] * vg[p * 8 + hh];
  }
}

// ---------------------------------------------------------------------------
// Kernel 5: attention. Block = (i-tile of 64 rows, b*h). 256 threads:
// thread t -> row i = t>>2, slice s = t&3 (16 j's each). q row in VGPRs.
// ---------------------------------------------------------------------------
__global__ __launch_bounds__(256) void k_attn(
    const float* __restrict__ q_r, const float* __restrict__ k_r, const float* __restrict__ v_r,
    const int* __restrict__ type_seq, const int* __restrict__ seq_time,
    const float* __restrict__ tpr, const float* __restrict__ tbw,
    const float* __restrict__ head_scale, BTab tb, float* __restrict__ ctx)
{
  int it = blockIdx.x, bh = blockIdx.y;
  int b = bh >> 3, h = bh & 7;
  int i0 = it << 6;
  int t = threadIdx.x;
  int i = t >> 2, s = t & 3;
  __shared__ float Ks[64][65], Vs[64][65];
  __shared__ float tabs[25], rabs[64], bnds[64];
  __shared__ int tis[64], Tis[64], tjs[64], Tjs[64];
  size_t hbase = (size_t)bh * (Ll * 64);

  // q row into registers (4 threads per row read the same row; L2-served)
  float qreg[64];
  {
    const float* src = q_r + hbase + (size_t)(i0 + i) * 64;
    #pragma unroll
    for (int q4 = 0; q4 < 16; ++q4) {
      float4 a = *reinterpret_cast<const float4*>(src + q4 * 4);
      qreg[q4 * 4 + 0] = a.x; qreg[q4 * 4 + 1] = a.y; qreg[q4 * 4 + 2] = a.z; qreg[q4 * 4 + 3] = a.w;
    }
  }
  if (t < 64)       { tis[t] = type_seq[b * Ll + i0 + t]; Tis[t] = seq_time[b * Ll + i0 + t]; }
  else if (t < 128) { int u = t - 64;  rabs[u] = tbw[u]; }
  else if (t < 192) { int u = t - 128; bnds[u] = (u < tb.nb) ? tb.bnd[u] : 3.0e38f; }
  else if (t < 217) { int u = t - 192; tabs[u] = tb.prior[u] + 0.25f * tanhf(tpr[h * 25 + u]); }
  float hs = head_scale[h];
  float acc[64];
  #pragma unroll
  for (int dd = 0; dd < 64; ++dd) acc[dd] = 0.f;

  for (int jt = 0; jt <= it; ++jt) {
    int j0 = jt << 6;
    __syncthreads();   // previous tile's compute done before overwrite
    {
      int r = t >> 2, c = s << 4;
      const float* ksrc = k_r + hbase + (size_t)(j0 + r) * 64 + c;
      const float* vsrc = v_r + hbase + (size_t)(j0 + r) * 64 + c;
      #pragma unroll
      for (int q4 = 0; q4 < 4; ++q4) {
        float4 a  = *reinterpret_cast<const float4*>(ksrc + q4 * 4);
        Ks[r][c + q4 * 4 + 0] = a.x; Ks[r][c + q4 * 4 + 1] = a.y;
        Ks[r][c + q4 * 4 + 2] = a.z; Ks[r][c + q4 * 4 + 3] = a.w;
        float4 vv = *reinterpret_cast<const float4*>(vsrc + q4 * 4);
        Vs[r][c + q4 * 4 + 0] = vv.x; Vs[r][c + q4 * 4 + 1] = vv.y;
        Vs[r][c + q4 * 4 + 2] = vv.z; Vs[r][c + q4 * 4 + 3] = vv.w;
      }
      if (t < 64) { tjs[t] = type_seq[b * Ll + j0 + t]; Tjs[t] = seq_time[b * Ll + j0 + t]; }
    }
    __syncthreads();
    float pj[16];
    #pragma unroll 4
    for (int jj = 0; jj < 16; ++jj) {
      int j = (s << 4) + jj;
      float d = 0.f;
      #pragma unroll
      for (int kk = 0; kk < 64; ++kk) d += qreg[kk] * Ks[j][kk];
      int gi = i0 + i, gj = j0 + j;
      float pv = 0.f;
      if ((gj <= gi) && (tis[i] != 0) && (tjs[j] != 0)) {
        int td = Tis[i] - Tjs[j]; td = (td < 0) ? -td : td; if (td < 1) td = 1;
        float tdf = (float)td;
        int lo = 0, hi = tb.nb;
        while (lo < hi) { int mid = (lo + hi) >> 1; if (bnds[mid] < tdf) lo = mid + 1; else hi = mid; }
        if (lo > 63) lo = 63;
        float lg = d * hs + 2.f * rabs[lo] + 4.f * tabs[tis[i] * 5 + tjs[j]];
        pv = lg / (1.f + expf(-lg));
      }
      pj[jj] = pv;
    }
    #pragma unroll 4
    for (int jj = 0; jj < 16; ++jj) {
      float pv = pj[jj];
      int j = (s << 4) + jj;
      #pragma unroll
      for (int dd = 0; dd < 64; ++dd) acc[dd] += pv * Vs[j][dd];
    }
  }
  // reduce partial ctx across the 4 slice-threads of each row (lanes i*4+s)
  #pragma unroll
  for (int dd = 0; dd < 64; ++dd) {
    acc[dd] += __shfl_xor(acc[dd], 1);
    acc[dd] += __shfl_xor(acc[dd], 2);
  }
  float* dst = ctx + hbase + (size_t)(i0 + i) * 64 + s * 16;
  #pragma unroll
  for (int dd = 0; dd < 16; ++dd) dst[dd] = acc[(s << 4) + dd];
}

// ---------------------------------------------------------------------------
// Kernel 6: LayerNorm(ctx) * u  (per position, 512 dims)
// ---------------------------------------------------------------------------
__global__ __launch_bounds__(256) void k_ln(
    const float* __restrict__ ctx, const float* __restrict__ uvqk,
    const float* __restrict__ ln_g, const float* __restrict__ ln_b,
    float* __restrict__ cw)
{
  int p = blockIdx.x; int b = p >> 10, l = p & 1023;
  int t = threadIdx.x;
  __shared__ float red[256];
  int d0 = t, d1 = t + 256;
  float v0 = ctx[(((size_t)(b * 8 + (d0 >> 6))) * 1024 + l) * 64 + (d0 & 63)];
  float v1 = ctx[(((size_t)(b * 8 + (d1 >> 6))) * 1024 + l) * 64 + (d1 & 63)];
  red[t] = v0 + v1;
  __syncthreads();
  for (int o = 128; o; o >>= 1) { if (t < o) red[t] += red[t + o]; __syncthreads(); }
  float mu = red[0] * (1.f / 512.f);
  __syncthreads();
  float e0 = v0 - mu, e1 = v1 - mu;
  red[t] = e0 * e0 + e1 * e1;
  __syncthreads();
  for (int o = 128; o; o >>= 1) { if (t < o) red[t] += red[t + o]; __syncthreads(); }
  float rs = rsqrtf(red[0] * (1.f / 512.f) + 1e-5f);
  cw[(size_t)p * 512 + d0] = (e0 * rs * ln_g[d0] + ln_b[d0]) * uvqk[(size_t)p * 2048 + d0];
  cw[(size_t)p * 512 + d1] = (e1 * rs * ln_g[d1] + ln_b[d1]) * uvqk[(size_t)p * 2048 + d1];
}

// ---------------------------------------------------------------------------
extern "C" void kernel_launch(void* const* d_in, const int* in_sizes, int n_in,
                              void* d_out, int out_size, void* d_ws, size_t ws_size,
                              hipStream_t stream)
{
  const float* x        = (const float*)d_in[0];
  const int*   type_seq = (const int*)d_in[1];
  const int*   seq_time = (const int*)d_in[2];
  const float* emb      = (const float*)d_in[3];
  const float* gW1 = (const float*)d_in[4];
  const float* gb1 = (const float*)d_in[5];
  const float* gW2 = (const float*)d_in[6];
  const float* gb2 = (const float*)d_in[7];
  const float* fW1 = (const float*)d_in[8];
  const float* fb1 = (const float*)d_in[9];
  const float* fW2 = (const float*)d_in[10];
  const float* fb2 = (const float*)d_in[11];
  const float* bW1 = (const float*)d_in[12];
  const float* bb1 = (const float*)d_in[13];
  const float* bW2 = (const float*)d_in[14];
  const float* bb2 = (const float*)d_in[15];
  const float* lW1 = (const float*)d_in[16];
  const float* lb1 = (const float*)d_in[17];
  const float* lW2 = (const float*)d_in[18];
  const float* lb2 = (const float*)d_in[19];
  const float* tpr = (const float*)d_in[20];
  const float* tbw = (const float*)d_in[21];
  const float* proj_w = (const float*)d_in[22];
  const float* proj_b = (const float*)d_in[23];
  const float* out_w  = (const float*)d_in[24];
  const float* out_b  = (const float*)d_in[25];
  const float* ln_g   = (const float*)d_in[26];
  const float* ln_b   = (const float*)d_in[27];
  const float* head_scale = (const float*)d_in[28];

  // workspace layout (floats)
  float* ws    = (float*)d_ws;
  float* x_new = ws;                          // 4M
  float* uvqk  = x_new + (size_t)4194304;     // 16M
  float* q_r   = uvqk + (size_t)16777216;     // 4M
  float* k_r   = q_r + (size_t)4194304;       // 4M
  float* v_r   = k_r + (size_t)4194304;       // 4M
  float* ctx   = v_r + (size_t)4194304;       // 4M
  float* qg    = ctx + (size_t)4194304;       // 64K
  float* kg    = qg + 65536;
  float* vg    = kg + 65536;
  float* rl    = vg + 65536;                  // 8K
  float* pos_  = rl + 8192;                   // 8K
  float* cw    = q_r;                         // reuse q_r after attention

  // host-side constant tables (deterministic, recomputed every call)
  BTab tb;
  {
    double step = log(86400.0 * 90.0) / 62.0;
    float vals[63];
    for (int i2 = 0; i2 < 63; ++i2) {
      double lp = exp(step * (double)i2);
      if (lp < 1.0) lp = 1.0;
      vals[i2] = (float)floor(lp);
    }
    int nb = 0; float prev = -1.f;
    for (int i2 = 0; i2 < 63; ++i2) if (vals[i2] != prev) { tb.bnd[nb++] = vals[i2]; prev = vals[i2]; }
    tb.nb = nb;
    for (int i2 = nb; i2 < 64; ++i2) tb.bnd[i2] = 3.0e38f;
    for (int i2 = 0; i2 < 25; ++i2) tb.prior[i2] = 0.f;
    tb.prior[1 * 5 + 1] = 0.05f;
    tb.prior[2 * 5 + 1] = 0.35f; tb.prior[2 * 5 + 2] = 0.05f;
    tb.prior[3 * 5 + 2] = 0.85f; tb.prior[3 * 5 + 1] = 0.25f; tb.prior[3 * 5 + 3] = 0.05f;
    tb.prior[4 * 5 + 3] = 1.2f;  tb.prior[4 * 5 + 2] = 0.8f;
    tb.prior[4 * 5 + 1] = 0.25f; tb.prior[4 * 5 + 4] = 0.1f;
  }

  k_pre<<<Bb * Ll, 256, 0, stream>>>(x, type_seq, seq_time, emb,
                                     gW1, gb1, gW2, gb2, fW1, fb1, fW2, fb2,
                                     bW1, bb1, bW2, bb2, lW1, lb1, lW2, lb2,
                                     x_new, qg, kg, vg, rl);
  k_scan<<<Bb, 1024, 0, stream>>>(rl, pos_);
  k_gemm<2048, 0><<<dim3(32, 128), 256, 0, stream>>>(x_new, proj_w, proj_b, nullptr, uvqk);
  k_rope<<<Bb * Ll, 256, 0, stream>>>(uvqk, pos_, qg, kg, vg, q_r, k_r, v_r);
  k_attn<<<dim3(16, 64), 256, 0, stream>>>(q_r, k_r, v_r, type_seq, seq_time,
                                           tpr, tbw, head_scale, tb, ctx);
  k_ln<<<Bb * Ll, 256, 0, stream>>>(ctx, uvqk, ln_g, ln_b, cw);
  k_gemm<512, 1><<<dim3(8, 128), 256, 0, stream>>>(cw, out_w, out_b, x_new, (float*)d_out);
}

// Round 2
// 726.894 us; speedup vs baseline: 2.1508x; 2.1508x over previous
//
#include <hip/hip_runtime.h>
#include <cmath>

// Problem constants
constexpr int Bb = 8, Hh = 8, Dd = 512, DHd = 64, Ll = 1024;

struct BTab { int nb; float bnd[64]; float prior[25]; };

__device__ __forceinline__ float silu_f(float v) { return v / (1.f + expf(-v)); }

// ---------------------------------------------------------------------------
// Kernel 1: per-position feature MLPs, gates, rope-lambda, x update
// ---------------------------------------------------------------------------
__global__ __launch_bounds__(256) void k_pre(
    const float* __restrict__ x, const int* __restrict__ type_seq, const int* __restrict__ seq_time,
    const float* __restrict__ emb,
    const float* __restrict__ gW1, const float* __restrict__ gb1,
    const float* __restrict__ gW2, const float* __restrict__ gb2,
    const float* __restrict__ fW1, const float* __restrict__ fb1,
    const float* __restrict__ fW2, const float* __restrict__ fb2,
    const float* __restrict__ bW1, const float* __restrict__ bb1,
    const float* __restrict__ bW2, const float* __restrict__ bb2,
    const float* __restrict__ lW1, const float* __restrict__ lb1,
    const float* __restrict__ lW2, const float* __restrict__ lb2,
    float* __restrict__ x_new, float* __restrict__ qg, float* __restrict__ kg,
    float* __restrict__ vg, float* __restrict__ rl)
{
  int p = blockIdx.x;              // b*L + l
  int l = p & (Ll - 1);
  int t = threadIdx.x;
  __shared__ float feat[17];
  __shared__ float hbuf[6][32];    // 0..2 qkv gates, 3 fusion, 4 bproj, 5 lam
  int ty = type_seq[p];
  float mf = (ty != 0) ? 1.f : 0.f;
  if (t < 16) {
    feat[t] = emb[ty * 16 + t];
  } else if (t == 16) {
    float dtf = 0.f;
    if (l > 0) { int dd = seq_time[p] - seq_time[p - 1]; if (dd < 0) dd = 0; dtf = (float)dd; }
    feat[16] = log1pf(dtf * mf);
  }
  __syncthreads();
  if (t < 192) {
    int m = t >> 5, u = t & 31;
    const float *W1, *b1;
    switch (m) {
      case 0: case 1: case 2: W1 = gW1 + m * 544; b1 = gb1 + m * 32; break;
      case 3: W1 = fW1; b1 = fb1; break;
      case 4: W1 = bW1; b1 = bb1; break;
      default: W1 = lW1; b1 = lb1; break;
    }
    float a = b1[u];
    #pragma unroll
    for (int f = 0; f < 17; ++f) a += feat[f] * W1[f * 32 + u];
    hbuf[m][u] = silu_f(a);
  }
  __syncthreads();
  if (t < 24) {
    int g = t >> 3, hd = t & 7;
    float a = gb2[g * 8 + hd];
    #pragma unroll
    for (int u = 0; u < 32; ++u) a += hbuf[g][u] * gW2[g * 256 + u * 8 + hd];
    float val = tanhf(a);
    float coef = (g == 2) ? 0.25f : 0.12f;
    float gate = mf * (1.f + coef * val) + (1.f - mf);   // pad -> 1.0
    float* dst = (g == 0) ? qg : (g == 1) ? kg : vg;
    dst[p * 8 + hd] = gate;
  } else if (t == 24) {
    float a = lb2[0];
    #pragma unroll
    for (int u = 0; u < 32; ++u) a += hbuf[5][u] * lW2[u];
    rl[p] = (1.f + 0.15f * tanhf(a)) * mf;               // pad -> 0
  }
  // fusion / bproj outputs (512 each), x update
  #pragma unroll
  for (int r = 0; r < 2; ++r) {
    int dd = t + (r << 8);
    float af = fb2[dd], ab = bb2[dd];
    #pragma unroll
    for (int u = 0; u < 32; ++u) {
      af += hbuf[3][u] * fW2[u * 512 + dd];
      ab += hbuf[4][u] * bW2[u * 512 + dd];
    }
    float fg = 1.f / (1.f + expf(-af));
    x_new[(size_t)p * 512 + dd] = x[(size_t)p * 512 + dd] + fg * (ab * mf);
  }
}

// ---------------------------------------------------------------------------
// Kernel 2: inclusive cumsum of rope-lambda along L (per batch row)
// ---------------------------------------------------------------------------
__global__ __launch_bounds__(1024) void k_scan(const float* __restrict__ rl, float* __restrict__ pos)
{
  int b = blockIdx.x, t = threadIdx.x;
  __shared__ float buf[1024];
  buf[t] = rl[b * 1024 + t];
  __syncthreads();
  for (int off = 1; off < 1024; off <<= 1) {
    float add = (t >= off) ? buf[t - off] : 0.f;
    __syncthreads();
    buf[t] += add;
    __syncthreads();
  }
  pos[b * 1024 + t] = buf[t];
}

// ---------------------------------------------------------------------------
// Kernel 3/7: fp32 tiled GEMM  C[M=8192, N] = A[M,512] @ W[512,N]  (+epilogue)
// MODE 0: C = silu(acc + bias)      MODE 1: C = acc + bias + add[row,col]
// ---------------------------------------------------------------------------
template <int N, int MODE>
__global__ __launch_bounds__(256) void k_gemm(
    const float* __restrict__ A, const float* __restrict__ W,
    const float* __restrict__ bias, const float* __restrict__ add,
    float* __restrict__ C)
{
  __shared__ float As[16][68];
  __shared__ float Ws[16][68];
  int t = threadIdx.x;
  int row0 = blockIdx.y * 64;
  int col0 = blockIdx.x * 64;
  int ty = t >> 4, tx = t & 15;
  int lm = t >> 2, lk = (t & 3) << 2;    // A-tile load: row lm, k offset lk (float4)
  int wk = t >> 4, wn = (t & 15) << 2;   // W-tile load: k row wk, col offset wn (float4)
  float acc[4][4];
  #pragma unroll
  for (int i = 0; i < 4; ++i)
    #pragma unroll
    for (int j = 0; j < 4; ++j) acc[i][j] = 0.f;

  for (int k0 = 0; k0 < 512; k0 += 16) {
    float4 av = *reinterpret_cast<const float4*>(A + (size_t)(row0 + lm) * 512 + k0 + lk);
    float4 wv = *reinterpret_cast<const float4*>(W + (size_t)(k0 + wk) * N + col0 + wn);
    __syncthreads();
    As[lk + 0][lm] = av.x; As[lk + 1][lm] = av.y; As[lk + 2][lm] = av.z; As[lk + 3][lm] = av.w;
    *reinterpret_cast<float4*>(&Ws[wk][wn]) = wv;
    __syncthreads();
    #pragma unroll
    for (int kk = 0; kk < 16; ++kk) {
      float a[4], bb[4];
      *reinterpret_cast<float4*>(a)  = *reinterpret_cast<const float4*>(&As[kk][ty * 4]);
      *reinterpret_cast<float4*>(bb) = *reinterpret_cast<const float4*>(&Ws[kk][tx * 4]);
      #pragma unroll
      for (int i = 0; i < 4; ++i)
        #pragma unroll
        for (int j = 0; j < 4; ++j) acc[i][j] += a[i] * bb[j];
    }
  }
  #pragma unroll
  for (int i = 0; i < 4; ++i) {
    int row = row0 + ty * 4 + i;
    #pragma unroll
    for (int j = 0; j < 4; ++j) {
      int col = col0 + tx * 4 + j;
      float c = acc[i][j] + bias[col];
      if (MODE == 0) c = c / (1.f + expf(-c));
      else           c += add[(size_t)row * N + col];
      C[(size_t)row * N + col] = c;
    }
  }
}

// ---------------------------------------------------------------------------
// Kernel 4: RoPE + gates, transpose into (B*H, L, 64)
// ---------------------------------------------------------------------------
__global__ __launch_bounds__(256) void k_rope(
    const float* __restrict__ uvqk, const float* __restrict__ pos,
    const float* __restrict__ qg, const float* __restrict__ kg, const float* __restrict__ vg,
    float* __restrict__ q_r, float* __restrict__ k_r, float* __restrict__ v_r)
{
  int p = blockIdx.x;
  int b = p >> 10, l = p & 1023;
  int t = threadIdx.x;
  int hd = t >> 5, dp = t & 31;
  const float* base = uvqk + (size_t)p * 2048;
  float ps = pos[p];
  float infq = powf(10000.f, -((float)(2 * dp)) / 64.f);
  float ang = ps * infq;
  float c = cosf(ang), sn = sinf(ang);
  float qe = base[1024 + hd * 64 + 2 * dp], qo = base[1024 + hd * 64 + 2 * dp + 1];
  float ke = base[1536 + hd * 64 + 2 * dp], ko = base[1536 + hd * 64 + 2 * dp + 1];
  float gq = qg[p * 8 + hd], gk = kg[p * 8 + hd];
  size_t ob = ((size_t)(b * 8 + hd) * 1024 + l) * 64;
  q_r[ob + dp]      = (qe * c - qo * sn) * gq;
  q_r[ob + 32 + dp] = (qe * sn + qo * c) * gq;
  k_r[ob + dp]      = (ke * c - ko * sn) * gk;
  k_r[ob + 32 + dp] = (ke * sn + ko * c) * gk;
  #pragma unroll
  for (int r = 0; r < 2; ++r) {
    int dd = t + (r << 8);
    int hh = dd >> 6;
    v_r[((size_t)(b * 8 + hh) * 1024 + l) * 64 + (dd & 63)] = base[512 + dd] * vg[p * 8 + hh];
  }
}

// ---------------------------------------------------------------------------
// Kernel 5: attention v2 — register-blocked 64x64 tiles, transposed LDS
// staging, vectorized ds_read_b128, balanced double-i-tile blocks.
// Block: 256 threads = 16x16; thread owns 4x4 outputs. Grid (8, 64):
// block px handles i-tiles {px, 15-px} -> exactly 17 j-tile iterations each.
// ---------------------------------------------------------------------------
__global__ __launch_bounds__(256) void k_attn(
    const float* __restrict__ q_r, const float* __restrict__ k_r, const float* __restrict__ v_r,
    const int* __restrict__ type_seq, const int* __restrict__ seq_time,
    const float* __restrict__ tpr, const float* __restrict__ tbw,
    const float* __restrict__ head_scale, BTab tb, float* __restrict__ ctx)
{
  int px = blockIdx.x, bh = blockIdx.y;
  int b = bh >> 3, h = bh & 7;
  int t = threadIdx.x;
  int ty = t >> 4, tx = t & 15;
  int ty4 = ty * 4, tx4 = tx * 4;
  __shared__ float Qts[64][68];   // Q^T : [kk][i]
  __shared__ float KPs[64][68];   // K^T : [kk][j]  then reused as P^T : [j][i]
  __shared__ float Vs[64][68];    // V   : [j][d]
  __shared__ float bnds[64], rabs[64], tabs[25];
  __shared__ int tis[64], Tis[64], tjs[64], Tjs[64];
  size_t hbase = (size_t)bh * (Ll * 64);

  if (t < 64)       { rabs[t] = tbw[t]; bnds[t] = (t < tb.nb) ? tb.bnd[t] : 3.0e38f; }
  else if (t < 89)  { int u = t - 64; tabs[u] = tb.prior[u] + 0.25f * tanhf(tpr[h * 25 + u]); }
  float hs = head_scale[h];

  int iload = t >> 2, sload = t & 3;   // staging role: row iload, 16-col chunk sload

  #pragma unroll
  for (int half = 0; half < 2; ++half) {
    int it = half ? (15 - px) : px;
    int i0 = it << 6;

    // ---- stage Q^T for this i-tile (safe: prior half done with Qts/tis) ----
    {
      const float* qsrc = q_r + hbase + (size_t)(i0 + iload) * 64 + sload * 16;
      #pragma unroll
      for (int q = 0; q < 4; ++q) {
        float4 v = *reinterpret_cast<const float4*>(qsrc + q * 4);
        int kk = sload * 16 + q * 4;
        Qts[kk + 0][iload] = v.x; Qts[kk + 1][iload] = v.y;
        Qts[kk + 2][iload] = v.z; Qts[kk + 3][iload] = v.w;
      }
      if (t < 64) { tis[t] = type_seq[b * Ll + i0 + t]; Tis[t] = seq_time[b * Ll + i0 + t]; }
    }

    float acc[4][4];
    #pragma unroll
    for (int r = 0; r < 4; ++r)
      #pragma unroll
      for (int c = 0; c < 4; ++c) acc[r][c] = 0.f;

    for (int jt = 0; jt <= it; ++jt) {
      int j0 = jt << 6;
      __syncthreads();   // prior tile's PV / Q-stage visible; safe to overwrite
      // ---- stage K^T (transpose on write) and V (row-major) ----
      {
        const float* ksrc = k_r + hbase + (size_t)(j0 + iload) * 64 + sload * 16;
        const float* vsrc = v_r + hbase + (size_t)(j0 + iload) * 64 + sload * 16;
        #pragma unroll
        for (int q = 0; q < 4; ++q) {
          float4 v = *reinterpret_cast<const float4*>(ksrc + q * 4);
          int kk = sload * 16 + q * 4;
          KPs[kk + 0][iload] = v.x; KPs[kk + 1][iload] = v.y;
          KPs[kk + 2][iload] = v.z; KPs[kk + 3][iload] = v.w;
          *reinterpret_cast<float4*>(&Vs[iload][sload * 16 + q * 4]) =
              *reinterpret_cast<const float4*>(vsrc + q * 4);
        }
        if (t < 64) { tjs[t] = type_seq[b * Ll + j0 + t]; Tjs[t] = seq_time[b * Ll + j0 + t]; }
      }
      __syncthreads();

      // ---- QK^T : 4x4 outer products over kk ----
      float pr[4][4];
      #pragma unroll
      for (int r = 0; r < 4; ++r)
        #pragma unroll
        for (int c = 0; c < 4; ++c) pr[r][c] = 0.f;
      #pragma unroll 16
      for (int kk = 0; kk < 64; ++kk) {
        float4 qv = *reinterpret_cast<const float4*>(&Qts[kk][ty4]);
        float4 kv = *reinterpret_cast<const float4*>(&KPs[kk][tx4]);
        const float* qa = reinterpret_cast<const float*>(&qv);
        const float* ka = reinterpret_cast<const float*>(&kv);
        #pragma unroll
        for (int r = 0; r < 4; ++r)
          #pragma unroll
          for (int c = 0; c < 4; ++c) pr[r][c] += qa[r] * ka[c];
      }

      // ---- bias + mask + silu ----
      #pragma unroll
      for (int r = 0; r < 4; ++r) {
        int gi = i0 + ty4 + r;
        int ti = tis[ty4 + r], Ti = Tis[ty4 + r];
        #pragma unroll
        for (int c = 0; c < 4; ++c) {
          int gj = j0 + tx4 + c;
          int tj = tjs[tx4 + c];
          float pv = 0.f;
          if ((gj <= gi) && (ti != 0) && (tj != 0)) {
            int td = Ti - Tjs[tx4 + c]; if (td < 0) td = -td; if (td < 1) td = 1;
            float tdf = (float)td;
            int lo = 0;
            #pragma unroll
            for (int st = 32; st >= 1; st >>= 1)
              if (bnds[lo + st - 1] < tdf) lo += st;
            float lg = pr[r][c] * hs + 2.f * rabs[lo] + 4.f * tabs[ti * 5 + tj];
            pv = lg / (1.f + expf(-lg));
          }
          pr[r][c] = pv;
        }
      }

      __syncthreads();   // all QK reads of KPs done before overwriting with P^T
      // ---- write P^T : KPs[j][i] ----
      #pragma unroll
      for (int c = 0; c < 4; ++c) {
        float4 w;
        w.x = pr[0][c]; w.y = pr[1][c]; w.z = pr[2][c]; w.w = pr[3][c];
        *reinterpret_cast<float4*>(&KPs[tx4 + c][ty4]) = w;
      }
      __syncthreads();

      // ---- PV : acc[r][c] += P[i][j] * V[j][d] ----
      #pragma unroll 16
      for (int j = 0; j < 64; ++j) {
        float4 pv = *reinterpret_cast<const float4*>(&KPs[j][ty4]);
        float4 vv = *reinterpret_cast<const float4*>(&Vs[j][tx4]);
        const float* pa = reinterpret_cast<const float*>(&pv);
        const float* va = reinterpret_cast<const float*>(&vv);
        #pragma unroll
        for (int r = 0; r < 4; ++r)
          #pragma unroll
          for (int c = 0; c < 4; ++c) acc[r][c] += pa[r] * va[c];
      }
    }

    // ---- write ctx tile ----
    #pragma unroll
    for (int r = 0; r < 4; ++r) {
      float4 o;
      o.x = acc[r][0]; o.y = acc[r][1]; o.z = acc[r][2]; o.w = acc[r][3];
      *reinterpret_cast<float4*>(ctx + hbase + (size_t)(i0 + ty4 + r) * 64 + tx4) = o;
    }
  }
}

// ---------------------------------------------------------------------------
// Kernel 6: LayerNorm(ctx) * u  (per position, 512 dims)
// ---------------------------------------------------------------------------
__global__ __launch_bounds__(256) void k_ln(
    const float* __restrict__ ctx, const float* __restrict__ uvqk,
    const float* __restrict__ ln_g, const float* __restrict__ ln_b,
    float* __restrict__ cw)
{
  int p = blockIdx.x; int b = p >> 10, l = p & 1023;
  int t = threadIdx.x;
  __shared__ float red[256];
  int d0 = t, d1 = t + 256;
  float v0 = ctx[(((size_t)(b * 8 + (d0 >> 6))) * 1024 + l) * 64 + (d0 & 63)];
  float v1 = ctx[(((size_t)(b * 8 + (d1 >> 6))) * 1024 + l) * 64 + (d1 & 63)];
  red[t] = v0 + v1;
  __syncthreads();
  for (int o = 128; o; o >>= 1) { if (t < o) red[t] += red[t + o]; __syncthreads(); }
  float mu = red[0] * (1.f / 512.f);
  __syncthreads();
  float e0 = v0 - mu, e1 = v1 - mu;
  red[t] = e0 * e0 + e1 * e1;
  __syncthreads();
  for (int o = 128; o; o >>= 1) { if (t < o) red[t] += red[t + o]; __syncthreads(); }
  float rs = rsqrtf(red[0] * (1.f / 512.f) + 1e-5f);
  cw[(size_t)p * 512 + d0] = (e0 * rs * ln_g[d0] + ln_b[d0]) * uvqk[(size_t)p * 2048 + d0];
  cw[(size_t)p * 512 + d1] = (e1 * rs * ln_g[d1] + ln_b[d1]) * uvqk[(size_t)p * 2048 + d1];
}

// ---------------------------------------------------------------------------
extern "C" void kernel_launch(void* const* d_in, const int* in_sizes, int n_in,
                              void* d_out, int out_size, void* d_ws, size_t ws_size,
                              hipStream_t stream)
{
  const float* x        = (const float*)d_in[0];
  const int*   type_seq = (const int*)d_in[1];
  const int*   seq_time = (const int*)d_in[2];
  const float* emb      = (const float*)d_in[3];
  const float* gW1 = (const float*)d_in[4];
  const float* gb1 = (const float*)d_in[5];
  const float* gW2 = (const float*)d_in[6];
  const float* gb2 = (const float*)d_in[7];
  const float* fW1 = (const float*)d_in[8];
  const float* fb1 = (const float*)d_in[9];
  const float* fW2 = (const float*)d_in[10];
  const float* fb2 = (const float*)d_in[11];
  const float* bW1 = (const float*)d_in[12];
  const float* bb1 = (const float*)d_in[13];
  const float* bW2 = (const float*)d_in[14];
  const float* bb2 = (const float*)d_in[15];
  const float* lW1 = (const float*)d_in[16];
  const float* lb1 = (const float*)d_in[17];
  const float* lW2 = (const float*)d_in[18];
  const float* lb2 = (const float*)d_in[19];
  const float* tpr = (const float*)d_in[20];
  const float* tbw = (const float*)d_in[21];
  const float* proj_w = (const float*)d_in[22];
  const float* proj_b = (const float*)d_in[23];
  const float* out_w  = (const float*)d_in[24];
  const float* out_b  = (const float*)d_in[25];
  const float* ln_g   = (const float*)d_in[26];
  const float* ln_b   = (const float*)d_in[27];
  const float* head_scale = (const float*)d_in[28];

  // workspace layout (floats)
  float* ws    = (float*)d_ws;
  float* x_new = ws;                          // 4M
  float* uvqk  = x_new + (size_t)4194304;     // 16M
  float* q_r   = uvqk + (size_t)16777216;     // 4M
  float* k_r   = q_r + (size_t)4194304;       // 4M
  float* v_r   = k_r + (size_t)4194304;       // 4M
  float* ctx   = v_r + (size_t)4194304;       // 4M
  float* qg    = ctx + (size_t)4194304;       // 64K
  float* kg    = qg + 65536;
  float* vg    = kg + 65536;
  float* rl    = vg + 65536;                  // 8K
  float* pos_  = rl + 8192;                   // 8K
  float* cw    = q_r;                         // reuse q_r after attention

  // host-side constant tables (deterministic, recomputed every call)
  BTab tb;
  {
    double step = log(86400.0 * 90.0) / 62.0;
    float vals[63];
    for (int i2 = 0; i2 < 63; ++i2) {
      double lp = exp(step * (double)i2);
      if (lp < 1.0) lp = 1.0;
      vals[i2] = (float)floor(lp);
    }
    int nb = 0; float prev = -1.f;
    for (int i2 = 0; i2 < 63; ++i2) if (vals[i2] != prev) { tb.bnd[nb++] = vals[i2]; prev = vals[i2]; }
    tb.nb = nb;
    for (int i2 = nb; i2 < 64; ++i2) tb.bnd[i2] = 3.0e38f;
    for (int i2 = 0; i2 < 25; ++i2) tb.prior[i2] = 0.f;
    tb.prior[1 * 5 + 1] = 0.05f;
    tb.prior[2 * 5 + 1] = 0.35f; tb.prior[2 * 5 + 2] = 0.05f;
    tb.prior[3 * 5 + 2] = 0.85f; tb.prior[3 * 5 + 1] = 0.25f; tb.prior[3 * 5 + 3] = 0.05f;
    tb.prior[4 * 5 + 3] = 1.2f;  tb.prior[4 * 5 + 2] = 0.8f;
    tb.prior[4 * 5 + 1] = 0.25f; tb.prior[4 * 5 + 4] = 0.1f;
  }

  k_pre<<<Bb * Ll, 256, 0, stream>>>(x, type_seq, seq_time, emb,
                                     gW1, gb1, gW2, gb2, fW1, fb1, fW2, fb2,
                                     bW1, bb1, bW2, bb2, lW1, lb1, lW2, lb2,
                                     x_new, qg, kg, vg, rl);
  k_scan<<<Bb, 1024, 0, stream>>>(rl, pos_);
  k_gemm<2048, 0><<<dim3(32, 128), 256, 0, stream>>>(x_new, proj_w, proj_b, nullptr, uvqk);
  k_rope<<<Bb * Ll, 256, 0, stream>>>(uvqk, pos_, qg, kg, vg, q_r, k_r, v_r);
  k_attn<<<dim3(8, 64), 256, 0, stream>>>(q_r, k_r, v_r, type_seq, seq_time,
                                          tpr, tbw, head_scale, tb, ctx);
  k_ln<<<Bb * Ll, 256, 0, stream>>>(ctx, uvqk, ln_g, ln_b, cw);
  k_gemm<512, 1><<<dim3(8, 128), 256, 0, stream>>>(cw, out_w, out_b, x_new, (float*)d_out);
}

// Round 3
// 359.009 us; speedup vs baseline: 4.3547x; 2.0247x over previous
//
#include <hip/hip_runtime.h>
#include <cmath>

constexpr int Bb = 8, Hh = 8, Dd = 512, DHd = 64, Ll = 1024;

struct BTab { int nb; float bnd[64]; float prior[25]; };

typedef __attribute__((ext_vector_type(8))) short bf16x8;
typedef __attribute__((ext_vector_type(4))) float f32x4;

__device__ __forceinline__ float silu_f(float v) { return v / (1.f + expf(-v)); }
__device__ __forceinline__ unsigned short f2b(float f) {
  unsigned u = __float_as_uint(f);
  unsigned r = (u + 0x7FFFu + ((u >> 16) & 1u)) >> 16;
  return (unsigned short)r;
}
__device__ __forceinline__ float b2f(unsigned short h) { return __uint_as_float(((unsigned)h) << 16); }

// ---------------------------------------------------------------------------
// Kernel: transpose f32 [K][N] -> bf16 [N][K]
// ---------------------------------------------------------------------------
__global__ __launch_bounds__(256) void k_conv(const float* __restrict__ in,
                                              unsigned short* __restrict__ out, int K, int N)
{
  __shared__ float tile[32][33];
  int n0 = blockIdx.x * 32, k0 = blockIdx.y * 32;
  int t = threadIdx.x; int c = t & 31, r0 = t >> 5;
  #pragma unroll
  for (int rr = 0; rr < 4; ++rr) { int r = r0 + rr * 8; tile[r][c] = in[(size_t)(k0 + r) * N + n0 + c]; }
  __syncthreads();
  #pragma unroll
  for (int rr = 0; rr < 4; ++rr) { int r = r0 + rr * 8; out[(size_t)(n0 + r) * K + k0 + c] = f2b(tile[c][r]); }
}

// ---------------------------------------------------------------------------
// Kernel 1: per-position feature MLPs, gates, rope-lambda, x update
// ---------------------------------------------------------------------------
__global__ __launch_bounds__(256) void k_pre(
    const float* __restrict__ x, const int* __restrict__ type_seq, const int* __restrict__ seq_time,
    const float* __restrict__ emb,
    const float* __restrict__ gW1, const float* __restrict__ gb1,
    const float* __restrict__ gW2, const float* __restrict__ gb2,
    const float* __restrict__ fW1, const float* __restrict__ fb1,
    const float* __restrict__ fW2, const float* __restrict__ fb2,
    const float* __restrict__ bW1, const float* __restrict__ bb1,
    const float* __restrict__ bW2, const float* __restrict__ bb2,
    const float* __restrict__ lW1, const float* __restrict__ lb1,
    const float* __restrict__ lW2, const float* __restrict__ lb2,
    float* __restrict__ x_new, unsigned short* __restrict__ x_new_bf,
    float* __restrict__ qg, float* __restrict__ kg,
    float* __restrict__ vg, float* __restrict__ rl)
{
  int p = blockIdx.x;              // b*L + l
  int l = p & (Ll - 1);
  int t = threadIdx.x;
  __shared__ float feat[17];
  __shared__ float hbuf[6][32];
  int ty = type_seq[p];
  float mf = (ty != 0) ? 1.f : 0.f;
  if (t < 16) {
    feat[t] = emb[ty * 16 + t];
  } else if (t == 16) {
    float dtf = 0.f;
    if (l > 0) { int dd = seq_time[p] - seq_time[p - 1]; if (dd < 0) dd = 0; dtf = (float)dd; }
    feat[16] = log1pf(dtf * mf);
  }
  __syncthreads();
  if (t < 192) {
    int m = t >> 5, u = t & 31;
    const float *W1, *b1;
    switch (m) {
      case 0: case 1: case 2: W1 = gW1 + m * 544; b1 = gb1 + m * 32; break;
      case 3: W1 = fW1; b1 = fb1; break;
      case 4: W1 = bW1; b1 = bb1; break;
      default: W1 = lW1; b1 = lb1; break;
    }
    float a = b1[u];
    #pragma unroll
    for (int f = 0; f < 17; ++f) a += feat[f] * W1[f * 32 + u];
    hbuf[m][u] = silu_f(a);
  }
  __syncthreads();
  if (t < 24) {
    int g = t >> 3, hd = t & 7;
    float a = gb2[g * 8 + hd];
    #pragma unroll
    for (int u = 0; u < 32; ++u) a += hbuf[g][u] * gW2[g * 256 + u * 8 + hd];
    float val = tanhf(a);
    float coef = (g == 2) ? 0.25f : 0.12f;
    float gate = mf * (1.f + coef * val) + (1.f - mf);
    float* dst = (g == 0) ? qg : (g == 1) ? kg : vg;
    dst[p * 8 + hd] = gate;
  } else if (t == 24) {
    float a = lb2[0];
    #pragma unroll
    for (int u = 0; u < 32; ++u) a += hbuf[5][u] * lW2[u];
    rl[p] = (1.f + 0.15f * tanhf(a)) * mf;
  }
  #pragma unroll
  for (int r = 0; r < 2; ++r) {
    int dd = t + (r << 8);
    float af = fb2[dd], ab = bb2[dd];
    #pragma unroll
    for (int u = 0; u < 32; ++u) {
      af += hbuf[3][u] * fW2[u * 512 + dd];
      ab += hbuf[4][u] * bW2[u * 512 + dd];
    }
    float fg = 1.f / (1.f + expf(-af));
    float xn = x[(size_t)p * 512 + dd] + fg * (ab * mf);
    x_new[(size_t)p * 512 + dd] = xn;
    x_new_bf[(size_t)p * 512 + dd] = f2b(xn);
  }
}

// ---------------------------------------------------------------------------
// Kernel 2: inclusive cumsum of rope-lambda along L (per batch row)
// ---------------------------------------------------------------------------
__global__ __launch_bounds__(1024) void k_scan(const float* __restrict__ rl, float* __restrict__ pos)
{
  int b = blockIdx.x, t = threadIdx.x;
  __shared__ float buf[1024];
  buf[t] = rl[b * 1024 + t];
  __syncthreads();
  for (int off = 1; off < 1024; off <<= 1) {
    float add = (t >= off) ? buf[t - off] : 0.f;
    __syncthreads();
    buf[t] += add;
    __syncthreads();
  }
  pos[b * 1024 + t] = buf[t];
}

// ---------------------------------------------------------------------------
// Kernel: precompute rb[b][i][j] = 2*tbw[bucket(|Ti-Tj|)] as bf16
// ---------------------------------------------------------------------------
__global__ __launch_bounds__(256) void k_bias(
    const int* __restrict__ seq_time, const float* __restrict__ tbw, BTab tb,
    unsigned short* __restrict__ rb)
{
  int i = blockIdx.x, b = blockIdx.y, t = threadIdx.x;
  __shared__ float bnds[64];
  __shared__ float rv[64];
  if (t < 64) { bnds[t] = (t < tb.nb) ? tb.bnd[t] : 3.0e38f; rv[t] = 2.f * tbw[t]; }
  __syncthreads();
  int Ti = seq_time[b * 1024 + i];
  int j = t * 4;
  const int* Tj = seq_time + b * 1024 + j;
  unsigned short o[4];
  #pragma unroll
  for (int q = 0; q < 4; ++q) {
    int td = Ti - Tj[q]; if (td < 0) td = -td; if (td < 1) td = 1;
    float tdf = (float)td;
    int lo = 0;
    #pragma unroll
    for (int st = 32; st; st >>= 1) if (bnds[lo + st - 1] < tdf) lo += st;
    if (lo > 63) lo = 63;
    o[q] = f2b(rv[lo]);
  }
  *reinterpret_cast<uint2*>(rb + (((size_t)b << 10) + i) * 1024 + j) = *reinterpret_cast<const uint2*>(o);
}

// ---------------------------------------------------------------------------
// MFMA GEMM: C[M,N] = epi(A_bf16[M,512] @ BT_bf16[N,512]^T + bias)
// MODE 0: C (bf16) = silu(acc+bias)   MODE 1: C (f32) = acc+bias+add
// Block 256 thr = 4 waves (2x2), tile 128x128, BK=32.
// ---------------------------------------------------------------------------
template <int N, int MODE>
__global__ __launch_bounds__(256) void k_gemm(
    const unsigned short* __restrict__ A, const unsigned short* __restrict__ BT,
    const float* __restrict__ bias, const float* __restrict__ add,
    void* __restrict__ Cv)
{
  __shared__ unsigned short As[128 * 40];
  __shared__ unsigned short Bs[128 * 40];
  int t = threadIdx.x;
  int w = t >> 6, l = t & 63, l15 = l & 15, lg = l >> 4;
  int wm = w >> 1, wn = w & 1;
  int row0 = blockIdx.y * 128, col0 = blockIdx.x * 128;
  f32x4 acc[4][4] = {};
  for (int k0 = 0; k0 < 512; k0 += 32) {
    __syncthreads();
    #pragma unroll
    for (int rep = 0; rep < 2; ++rep) {
      int idx = t + rep * 256;
      int row = idx >> 2, c = idx & 3;
      uint4 av = *reinterpret_cast<const uint4*>(A + (size_t)(row0 + row) * 512 + k0 + c * 8);
      *reinterpret_cast<uint4*>(&As[row * 40 + c * 8]) = av;
      uint4 bv = *reinterpret_cast<const uint4*>(BT + (size_t)(col0 + row) * 512 + k0 + c * 8);
      *reinterpret_cast<uint4*>(&Bs[row * 40 + c * 8]) = bv;
    }
    __syncthreads();
    bf16x8 af[4], bfr[4];
    #pragma unroll
    for (int mf = 0; mf < 4; ++mf)
      af[mf] = *reinterpret_cast<const bf16x8*>(&As[(wm * 64 + mf * 16 + l15) * 40 + lg * 8]);
    #pragma unroll
    for (int nf = 0; nf < 4; ++nf)
      bfr[nf] = *reinterpret_cast<const bf16x8*>(&Bs[(wn * 64 + nf * 16 + l15) * 40 + lg * 8]);
    #pragma unroll
    for (int mf = 0; mf < 4; ++mf)
      #pragma unroll
      for (int nf = 0; nf < 4; ++nf)
        acc[mf][nf] = __builtin_amdgcn_mfma_f32_16x16x32_bf16(af[mf], bfr[nf], acc[mf][nf], 0, 0, 0);
  }
  #pragma unroll
  for (int mf = 0; mf < 4; ++mf)
    #pragma unroll
    for (int nf = 0; nf < 4; ++nf)
      #pragma unroll
      for (int r = 0; r < 4; ++r) {
        int row = row0 + wm * 64 + mf * 16 + lg * 4 + r;
        int col = col0 + wn * 64 + nf * 16 + l15;
        float c = acc[mf][nf][r] + bias[col];
        if (MODE == 0) {
          c = c / (1.f + expf(-c));
          ((unsigned short*)Cv)[(size_t)row * N + col] = f2b(c);
        } else {
          ((float*)Cv)[(size_t)row * N + col] = c + add[(size_t)row * N + col];
        }
      }
}

// ---------------------------------------------------------------------------
// Kernel 4: RoPE + gates, bf16 in (uvqk) -> bf16 out, transpose to (B*H,L,64)
// ---------------------------------------------------------------------------
__global__ __launch_bounds__(256) void k_rope(
    const unsigned short* __restrict__ uvqk, const float* __restrict__ pos,
    const float* __restrict__ qg, const float* __restrict__ kg, const float* __restrict__ vg,
    unsigned short* __restrict__ q_r, unsigned short* __restrict__ k_r, unsigned short* __restrict__ v_r)
{
  int p = blockIdx.x;
  int b = p >> 10, l = p & 1023;
  int t = threadIdx.x;
  int hd = t >> 5, dp = t & 31;
  const unsigned short* base = uvqk + (size_t)p * 2048;
  float ps = pos[p];
  float infq = powf(10000.f, -((float)(2 * dp)) / 64.f);
  float ang = ps * infq;
  float c = cosf(ang), sn = sinf(ang);
  float qe = b2f(base[1024 + hd * 64 + 2 * dp]), qo = b2f(base[1024 + hd * 64 + 2 * dp + 1]);
  float ke = b2f(base[1536 + hd * 64 + 2 * dp]), ko = b2f(base[1536 + hd * 64 + 2 * dp + 1]);
  float gq = qg[p * 8 + hd], gk = kg[p * 8 + hd];
  size_t ob = ((size_t)(b * 8 + hd) * 1024 + l) * 64;
  q_r[ob + dp]      = f2b((qe * c - qo * sn) * gq);
  q_r[ob + 32 + dp] = f2b((qe * sn + qo * c) * gq);
  k_r[ob + dp]      = f2b((ke * c - ko * sn) * gk);
  k_r[ob + 32 + dp] = f2b((ke * sn + ko * c) * gk);
  #pragma unroll
  for (int r = 0; r < 2; ++r) {
    int dd = t + (r << 8);
    int hh = dd >> 6;
    v_r[((size_t)(b * 8 + hh) * 1024 + l) * 64 + (dd & 63)] = f2b(b2f(base[512 + dd]) * vg[p * 8 + hh]);
  }
}

// ---------------------------------------------------------------------------
// Kernel 5: attention via MFMA. Grid (8, 64): block px does i-tiles {px,15-px}.
// 4 waves: wave w owns rows w*16..w*16+15 of the 64-row i-tile, all 64 cols.
// LDS rows stride 72 elems (144B) for aligned b128 + low bank conflict.
// ---------------------------------------------------------------------------
__global__ __launch_bounds__(256) void k_attn(
    const unsigned short* __restrict__ q_bf, const unsigned short* __restrict__ k_bf,
    const unsigned short* __restrict__ v_bf,
    const int* __restrict__ type_seq, const unsigned short* __restrict__ rb,
    const float* __restrict__ tpr, const float* __restrict__ head_scale,
    BTab tb, float* __restrict__ ctx)
{
  int px = blockIdx.x, bh = blockIdx.y;
  int b = bh >> 3, h = bh & 7;
  int t = threadIdx.x;
  int w = t >> 6, l = t & 63, l15 = l & 15, lg = l >> 4;
  __shared__ unsigned short Qs[64 * 72];
  __shared__ unsigned short Ks[64 * 72];
  __shared__ unsigned short Vts[64 * 72];
  __shared__ unsigned short Ps[64 * 72];
  __shared__ float tabs4[25];
  __shared__ int tis[64], tjs[64];
  size_t hb = (size_t)bh * 65536;
  if (t < 25) tabs4[t] = 4.f * (tb.prior[t] + 0.25f * tanhf(tpr[h * 25 + t]));
  float hs = head_scale[h];

  #pragma unroll
  for (int half = 0; half < 2; ++half) {
    int it = half ? (15 - px) : px;
    int i0 = it << 6;
    __syncthreads();   // prior half fully done with LDS / tis
    {
      int row = t >> 2, c4 = t & 3;
      const uint4* src = reinterpret_cast<const uint4*>(q_bf + hb + (size_t)(i0 + row) * 64 + c4 * 16);
      uint4 a = src[0], b4 = src[1];
      *reinterpret_cast<uint4*>(&Qs[row * 72 + c4 * 16]) = a;
      *reinterpret_cast<uint4*>(&Qs[row * 72 + c4 * 16 + 8]) = b4;
      if (t < 64) tis[t] = type_seq[b * 1024 + i0 + t];
    }
    f32x4 Dacc[4] = {};

    for (int jt = 0; jt <= it; ++jt) {
      int j0 = jt << 6;
      __syncthreads();   // prior tile reads done (also covers Q staging)
      #pragma unroll
      for (int rep = 0; rep < 2; ++rep) {
        int idx = t + rep * 256;
        int row = idx >> 3, c = idx & 7;
        uint4 kv = *reinterpret_cast<const uint4*>(k_bf + hb + (size_t)(j0 + row) * 64 + c * 8);
        *reinterpret_cast<uint4*>(&Ks[row * 72 + c * 8]) = kv;
      }
      {
        int j = t >> 2, s = t & 3;
        const unsigned short* vs = v_bf + hb + (size_t)(j0 + j) * 64 + s * 16;
        uint4 a = *reinterpret_cast<const uint4*>(vs);
        uint4 b4 = *reinterpret_cast<const uint4*>(vs + 8);
        const unsigned short* ua = reinterpret_cast<const unsigned short*>(&a);
        const unsigned short* ub = reinterpret_cast<const unsigned short*>(&b4);
        #pragma unroll
        for (int e = 0; e < 8; ++e) {
          int d = s * 16 + e;
          Vts[(d * 72 + j) ^ ((d >> 4) << 3)] = ua[e];
          int d2 = s * 16 + 8 + e;
          Vts[(d2 * 72 + j) ^ ((d2 >> 4) << 3)] = ub[e];
        }
        if (t < 64) tjs[t] = type_seq[b * 1024 + j0 + t];
      }
      __syncthreads();

      // ---- QK^T ----
      bf16x8 qf0 = *reinterpret_cast<const bf16x8*>(&Qs[(w * 16 + l15) * 72 + lg * 8]);
      bf16x8 qf1 = *reinterpret_cast<const bf16x8*>(&Qs[(w * 16 + l15) * 72 + lg * 8 + 32]);
      f32x4 S[4] = {};
      #pragma unroll
      for (int nf = 0; nf < 4; ++nf) {
        bf16x8 kf0 = *reinterpret_cast<const bf16x8*>(&Ks[(nf * 16 + l15) * 72 + lg * 8]);
        bf16x8 kf1 = *reinterpret_cast<const bf16x8*>(&Ks[(nf * 16 + l15) * 72 + lg * 8 + 32]);
        S[nf] = __builtin_amdgcn_mfma_f32_16x16x32_bf16(qf0, kf0, S[nf], 0, 0, 0);
        S[nf] = __builtin_amdgcn_mfma_f32_16x16x32_bf16(qf1, kf1, S[nf], 0, 0, 0);
      }
      // ---- bias + mask + silu, P -> LDS (bf16) ----
      #pragma unroll
      for (int nf = 0; nf < 4; ++nf) {
        int jl = nf * 16 + l15, gj = j0 + jl;
        int tj = tjs[jl];
        #pragma unroll
        for (int r = 0; r < 4; ++r) {
          int il = w * 16 + lg * 4 + r, gi = i0 + il;
          int ti = tis[il];
          float p = 0.f;
          if ((gj <= gi) && (ti != 0) && (tj != 0)) {
            float rbv = b2f(rb[(((size_t)b << 10) + gi) * 1024 + gj]);
            float lgt = S[nf][r] * hs + rbv + tabs4[ti * 5 + tj];
            p = lgt / (1.f + expf(-lgt));
          }
          Ps[il * 72 + jl] = f2b(p);
        }
      }
      __syncthreads();

      // ---- PV ----
      bf16x8 pf0 = *reinterpret_cast<const bf16x8*>(&Ps[(w * 16 + l15) * 72 + lg * 8]);
      bf16x8 pf1 = *reinterpret_cast<const bf16x8*>(&Ps[(w * 16 + l15) * 72 + lg * 8 + 32]);
      #pragma unroll
      for (int nf = 0; nf < 4; ++nf) {
        int d = nf * 16 + l15;
        int e0 = (d * 72 + lg * 8) ^ ((d >> 4) << 3);
        int e1 = (d * 72 + 32 + lg * 8) ^ ((d >> 4) << 3);
        bf16x8 vf0 = *reinterpret_cast<const bf16x8*>(&Vts[e0]);
        bf16x8 vf1 = *reinterpret_cast<const bf16x8*>(&Vts[e1]);
        Dacc[nf] = __builtin_amdgcn_mfma_f32_16x16x32_bf16(pf0, vf0, Dacc[nf], 0, 0, 0);
        Dacc[nf] = __builtin_amdgcn_mfma_f32_16x16x32_bf16(pf1, vf1, Dacc[nf], 0, 0, 0);
      }
    }
    // ---- write ctx (f32) ----
    #pragma unroll
    for (int nf = 0; nf < 4; ++nf)
      #pragma unroll
      for (int r = 0; r < 4; ++r) {
        int gi = i0 + w * 16 + lg * 4 + r;
        ctx[hb + (size_t)gi * 64 + nf * 16 + l15] = Dacc[nf][r];
      }
  }
}

// ---------------------------------------------------------------------------
// Kernel 6: LayerNorm(ctx) * u -> cw (bf16)
// ---------------------------------------------------------------------------
__global__ __launch_bounds__(256) void k_ln(
    const float* __restrict__ ctx, const unsigned short* __restrict__ uvqk,
    const float* __restrict__ ln_g, const float* __restrict__ ln_b,
    unsigned short* __restrict__ cw)
{
  int p = blockIdx.x; int b = p >> 10, l = p & 1023;
  int t = threadIdx.x;
  __shared__ float red[256];
  int d0 = t, d1 = t + 256;
  float v0 = ctx[(((size_t)(b * 8 + (d0 >> 6))) * 1024 + l) * 64 + (d0 & 63)];
  float v1 = ctx[(((size_t)(b * 8 + (d1 >> 6))) * 1024 + l) * 64 + (d1 & 63)];
  red[t] = v0 + v1;
  __syncthreads();
  for (int o = 128; o; o >>= 1) { if (t < o) red[t] += red[t + o]; __syncthreads(); }
  float mu = red[0] * (1.f / 512.f);
  __syncthreads();
  float e0 = v0 - mu, e1 = v1 - mu;
  red[t] = e0 * e0 + e1 * e1;
  __syncthreads();
  for (int o = 128; o; o >>= 1) { if (t < o) red[t] += red[t + o]; __syncthreads(); }
  float rs = rsqrtf(red[0] * (1.f / 512.f) + 1e-5f);
  float u0 = b2f(uvqk[(size_t)p * 2048 + d0]);
  float u1 = b2f(uvqk[(size_t)p * 2048 + d1]);
  cw[(size_t)p * 512 + d0] = f2b((e0 * rs * ln_g[d0] + ln_b[d0]) * u0);
  cw[(size_t)p * 512 + d1] = f2b((e1 * rs * ln_g[d1] + ln_b[d1]) * u1);
}

// ---------------------------------------------------------------------------
extern "C" void kernel_launch(void* const* d_in, const int* in_sizes, int n_in,
                              void* d_out, int out_size, void* d_ws, size_t ws_size,
                              hipStream_t stream)
{
  const float* x        = (const float*)d_in[0];
  const int*   type_seq = (const int*)d_in[1];
  const int*   seq_time = (const int*)d_in[2];
  const float* emb      = (const float*)d_in[3];
  const float* gW1 = (const float*)d_in[4];
  const float* gb1 = (const float*)d_in[5];
  const float* gW2 = (const float*)d_in[6];
  const float* gb2 = (const float*)d_in[7];
  const float* fW1 = (const float*)d_in[8];
  const float* fb1 = (const float*)d_in[9];
  const float* fW2 = (const float*)d_in[10];
  const float* fb2 = (const float*)d_in[11];
  const float* bW1 = (const float*)d_in[12];
  const float* bb1 = (const float*)d_in[13];
  const float* bW2 = (const float*)d_in[14];
  const float* bb2 = (const float*)d_in[15];
  const float* lW1 = (const float*)d_in[16];
  const float* lb1 = (const float*)d_in[17];
  const float* lW2 = (const float*)d_in[18];
  const float* lb2 = (const float*)d_in[19];
  const float* tpr = (const float*)d_in[20];
  const float* tbw = (const float*)d_in[21];
  const float* proj_w = (const float*)d_in[22];
  const float* proj_b = (const float*)d_in[23];
  const float* out_w  = (const float*)d_in[24];
  const float* out_b  = (const float*)d_in[25];
  const float* ln_g   = (const float*)d_in[26];
  const float* ln_b   = (const float*)d_in[27];
  const float* head_scale = (const float*)d_in[28];

  // workspace layout (byte-based)
  char* W = (char*)d_ws;
  float* x_new = (float*)W;                 W += (size_t)4194304 * 4;
  unsigned short* uvqk = (unsigned short*)W; W += (size_t)16777216 * 2;
  float* ctx = (float*)W;                   W += (size_t)4194304 * 4;
  unsigned short* q_bf = (unsigned short*)W; W += (size_t)4194304 * 2;
  unsigned short* k_bf = (unsigned short*)W; W += (size_t)4194304 * 2;
  unsigned short* v_bf = (unsigned short*)W; W += (size_t)4194304 * 2;
  unsigned short* cw_bf = (unsigned short*)W; W += (size_t)4194304 * 2;
  unsigned short* xbf = (unsigned short*)W;  W += (size_t)4194304 * 2;
  unsigned short* pwT = (unsigned short*)W;  W += (size_t)1048576 * 2;
  unsigned short* owT = (unsigned short*)W;  W += (size_t)262144 * 2;
  unsigned short* rb  = (unsigned short*)W;  W += (size_t)8388608 * 2;
  float* qg = (float*)W;   W += (size_t)65536 * 4;
  float* kg = (float*)W;   W += (size_t)65536 * 4;
  float* vg = (float*)W;   W += (size_t)65536 * 4;
  float* rl = (float*)W;   W += (size_t)8192 * 4;
  float* pos_ = (float*)W; W += (size_t)8192 * 4;

  BTab tb;
  {
    double step = log(86400.0 * 90.0) / 62.0;
    float vals[63];
    for (int i2 = 0; i2 < 63; ++i2) {
      double lp = exp(step * (double)i2);
      if (lp < 1.0) lp = 1.0;
      vals[i2] = (float)floor(lp);
    }
    int nb = 0; float prev = -1.f;
    for (int i2 = 0; i2 < 63; ++i2) if (vals[i2] != prev) { tb.bnd[nb++] = vals[i2]; prev = vals[i2]; }
    tb.nb = nb;
    for (int i2 = nb; i2 < 64; ++i2) tb.bnd[i2] = 3.0e38f;
    for (int i2 = 0; i2 < 25; ++i2) tb.prior[i2] = 0.f;
    tb.prior[1 * 5 + 1] = 0.05f;
    tb.prior[2 * 5 + 1] = 0.35f; tb.prior[2 * 5 + 2] = 0.05f;
    tb.prior[3 * 5 + 2] = 0.85f; tb.prior[3 * 5 + 1] = 0.25f; tb.prior[3 * 5 + 3] = 0.05f;
    tb.prior[4 * 5 + 3] = 1.2f;  tb.prior[4 * 5 + 2] = 0.8f;
    tb.prior[4 * 5 + 1] = 0.25f; tb.prior[4 * 5 + 4] = 0.1f;
  }

  k_conv<<<dim3(64, 16), 256, 0, stream>>>(proj_w, pwT, 512, 2048);
  k_conv<<<dim3(16, 16), 256, 0, stream>>>(out_w, owT, 512, 512);
  k_pre<<<Bb * Ll, 256, 0, stream>>>(x, type_seq, seq_time, emb,
                                     gW1, gb1, gW2, gb2, fW1, fb1, fW2, fb2,
                                     bW1, bb1, bW2, bb2, lW1, lb1, lW2, lb2,
                                     x_new, xbf, qg, kg, vg, rl);
  k_scan<<<Bb, 1024, 0, stream>>>(rl, pos_);
  k_bias<<<dim3(Ll, Bb), 256, 0, stream>>>(seq_time, tbw, tb, rb);
  k_gemm<2048, 0><<<dim3(16, 64), 256, 0, stream>>>(xbf, pwT, proj_b, nullptr, (void*)uvqk);
  k_rope<<<Bb * Ll, 256, 0, stream>>>(uvqk, pos_, qg, kg, vg, q_bf, k_bf, v_bf);
  k_attn<<<dim3(8, 64), 256, 0, stream>>>(q_bf, k_bf, v_bf, type_seq, rb,
                                          tpr, head_scale, tb, ctx);
  k_ln<<<Bb * Ll, 256, 0, stream>>>(ctx, uvqk, ln_g, ln_b, cw_bf);
  k_gemm<512, 1><<<dim3(4, 64), 256, 0, stream>>>(cw_bf, owT, out_b, x_new, d_out);
}

// Round 5
// 324.401 us; speedup vs baseline: 4.8193x; 1.1067x over previous
//
#include <hip/hip_runtime.h>
#include <cmath>

constexpr int Bb = 8, Hh = 8, Dd = 512, DHd = 64, Ll = 1024;

struct BTab { int nb; float bnd[64]; float prior[25]; };

typedef __attribute__((ext_vector_type(8))) short bf16x8;
typedef __attribute__((ext_vector_type(4))) float f32x4;

__device__ __forceinline__ float silu_f(float v) { return v / (1.f + expf(-v)); }
__device__ __forceinline__ unsigned short f2b(float f) {
  unsigned u = __float_as_uint(f);
  unsigned r = (u + 0x7FFFu + ((u >> 16) & 1u)) >> 16;
  return (unsigned short)r;
}
__device__ __forceinline__ float b2f(unsigned short h) { return __uint_as_float(((unsigned)h) << 16); }

// ---------------------------------------------------------------------------
// transpose f32 [K][N] -> bf16 [N][K]
// ---------------------------------------------------------------------------
__global__ __launch_bounds__(256) void k_conv(const float* __restrict__ in,
                                              unsigned short* __restrict__ out, int K, int N)
{
  __shared__ float tile[32][33];
  int n0 = blockIdx.x * 32, k0 = blockIdx.y * 32;
  int t = threadIdx.x; int c = t & 31, r0 = t >> 5;
  #pragma unroll
  for (int rr = 0; rr < 4; ++rr) { int r = r0 + rr * 8; tile[r][c] = in[(size_t)(k0 + r) * N + n0 + c]; }
  __syncthreads();
  #pragma unroll
  for (int rr = 0; rr < 4; ++rr) { int r = r0 + rr * 8; out[(size_t)(n0 + r) * K + k0 + c] = f2b(tile[c][r]); }
}

// ---------------------------------------------------------------------------
// Kernel 1: per-position feature MLPs, gates, rope-lambda, x update.
// 8 positions per block (amortizes fW2/bW2 panel reads 8x).
// ---------------------------------------------------------------------------
__global__ __launch_bounds__(256) void k_pre(
    const float* __restrict__ x, const int* __restrict__ type_seq, const int* __restrict__ seq_time,
    const float* __restrict__ emb,
    const float* __restrict__ gW1, const float* __restrict__ gb1,
    const float* __restrict__ gW2, const float* __restrict__ gb2,
    const float* __restrict__ fW1, const float* __restrict__ fb1,
    const float* __restrict__ fW2, const float* __restrict__ fb2,
    const float* __restrict__ bW1, const float* __restrict__ bb1,
    const float* __restrict__ bW2, const float* __restrict__ bb2,
    const float* __restrict__ lW1, const float* __restrict__ lb1,
    const float* __restrict__ lW2, const float* __restrict__ lb2,
    float* __restrict__ x_new, unsigned short* __restrict__ x_new_bf,
    float* __restrict__ qg, float* __restrict__ kg,
    float* __restrict__ vg, float* __restrict__ rl)
{
  int p0 = blockIdx.x * 8;
  int t = threadIdx.x;
  __shared__ float feat[8][17];
  __shared__ float hbuf[8][6][32];
  __shared__ float mfs[8];
  int q = t >> 5, u = t & 31;
  int ty = type_seq[p0 + q];
  float mf = (ty != 0) ? 1.f : 0.f;
  if (u < 16) {
    feat[q][u] = emb[ty * 16 + u];
  } else if (u == 16) {
    int p = p0 + q, l = p & (Ll - 1);
    float dtf = 0.f;
    if (l > 0) { int dd = seq_time[p] - seq_time[p - 1]; if (dd < 0) dd = 0; dtf = (float)dd; }
    feat[q][16] = log1pf(dtf * mf);
  } else if (u == 17) {
    mfs[q] = mf;
  }
  __syncthreads();
  #pragma unroll
  for (int m = 0; m < 6; ++m) {
    const float *W1, *b1;
    switch (m) {
      case 0: case 1: case 2: W1 = gW1 + m * 544; b1 = gb1 + m * 32; break;
      case 3: W1 = fW1; b1 = fb1; break;
      case 4: W1 = bW1; b1 = bb1; break;
      default: W1 = lW1; b1 = lb1; break;
    }
    float a = b1[u];
    #pragma unroll
    for (int f = 0; f < 17; ++f) a += feat[q][f] * W1[f * 32 + u];
    hbuf[q][m][u] = silu_f(a);
  }
  __syncthreads();
  if (t < 200) {
    int qq = t / 25, j = t - qq * 25;
    int p = p0 + qq; float m2 = mfs[qq];
    if (j < 24) {
      int g = j >> 3, hd = j & 7;
      float a = gb2[g * 8 + hd];
      #pragma unroll
      for (int uu = 0; uu < 32; ++uu) a += hbuf[qq][g][uu] * gW2[g * 256 + uu * 8 + hd];
      float coef = (g == 2) ? 0.25f : 0.12f;
      float gate = m2 * (1.f + coef * tanhf(a)) + (1.f - m2);
      float* dst = (g == 0) ? qg : (g == 1) ? kg : vg;
      dst[p * 8 + hd] = gate;
    } else {
      float a = lb2[0];
      #pragma unroll
      for (int uu = 0; uu < 32; ++uu) a += hbuf[qq][5][uu] * lW2[uu];
      rl[p] = (1.f + 0.15f * tanhf(a)) * m2;
    }
  }
  #pragma unroll
  for (int r = 0; r < 2; ++r) {
    int dd = t + (r << 8);
    float af[8], ab[8];
    #pragma unroll
    for (int q8 = 0; q8 < 8; ++q8) { af[q8] = 0.f; ab[q8] = 0.f; }
    for (int uu = 0; uu < 32; ++uu) {
      float wf = fW2[uu * 512 + dd], wb = bW2[uu * 512 + dd];
      #pragma unroll
      for (int q8 = 0; q8 < 8; ++q8) {
        af[q8] += hbuf[q8][3][uu] * wf;
        ab[q8] += hbuf[q8][4][uu] * wb;
      }
    }
    float fb = fb2[dd], bb = bb2[dd];
    #pragma unroll
    for (int q8 = 0; q8 < 8; ++q8) {
      int p = p0 + q8;
      float fg = 1.f / (1.f + expf(-(af[q8] + fb)));
      float xn = x[(size_t)p * 512 + dd] + fg * ((ab[q8] + bb) * mfs[q8]);
      x_new[(size_t)p * 512 + dd] = xn;
      x_new_bf[(size_t)p * 512 + dd] = f2b(xn);
    }
  }
}

// ---------------------------------------------------------------------------
// Kernel 2: inclusive cumsum of rope-lambda along L (per batch row)
// ---------------------------------------------------------------------------
__global__ __launch_bounds__(1024) void k_scan(const float* __restrict__ rl, float* __restrict__ pos)
{
  int b = blockIdx.x, t = threadIdx.x;
  __shared__ float buf[1024];
  buf[t] = rl[b * 1024 + t];
  __syncthreads();
  for (int off = 1; off < 1024; off <<= 1) {
    float add = (t >= off) ? buf[t - off] : 0.f;
    __syncthreads();
    buf[t] += add;
    __syncthreads();
  }
  pos[b * 1024 + t] = buf[t];
}

// ---------------------------------------------------------------------------
// k_bias: rb2 in per-thread MFMA fragment layout.
// rb2[(b*136 + tri(it,jt)) * 4096 + t*16 + (nf*4+r)]  (bf16, = 2*tbw[bucket])
// ---------------------------------------------------------------------------
__global__ __launch_bounds__(256) void k_bias(
    const int* __restrict__ seq_time, const float* __restrict__ tbw, BTab tb,
    unsigned short* __restrict__ rb2)
{
  int f = blockIdx.x, b = blockIdx.y, t = threadIdx.x;
  int it = 0;
  while ((it + 1) * (it + 2) / 2 <= f) ++it;
  int jt = f - it * (it + 1) / 2;
  __shared__ float bnds[64], rv[64];
  __shared__ int Tis[64], Tjs[64];
  if (t < 64) {
    bnds[t] = (t < tb.nb) ? tb.bnd[t] : 3.0e38f;
    rv[t] = 2.f * tbw[t];
    Tis[t] = seq_time[b * 1024 + it * 64 + t];
    Tjs[t] = seq_time[b * 1024 + jt * 64 + t];
  }
  __syncthreads();
  int w = t >> 6, lg = (t >> 4) & 3, l15 = t & 15;
  unsigned short o[16];
  #pragma unroll
  for (int nf = 0; nf < 4; ++nf) {
    int jl = nf * 16 + l15;
    int Tj = Tjs[jl];
    #pragma unroll
    for (int r = 0; r < 4; ++r) {
      int il = w * 16 + lg * 4 + r;
      int td = Tis[il] - Tj; if (td < 0) td = -td; if (td < 1) td = 1;
      float tdf = (float)td;
      int lo = 0;
      #pragma unroll
      for (int st = 32; st; st >>= 1) if (bnds[lo + st - 1] < tdf) lo += st;
      if (lo > 63) lo = 63;
      o[nf * 4 + r] = f2b(rv[lo]);
    }
  }
  unsigned short* dst = rb2 + ((size_t)(b * 136 + f)) * 4096 + t * 16;
  *reinterpret_cast<uint4*>(dst) = *reinterpret_cast<const uint4*>(&o[0]);
  *reinterpret_cast<uint4*>(dst + 8) = *reinterpret_cast<const uint4*>(&o[8]);
}

// ---------------------------------------------------------------------------
// MFMA GEMM: C[M,N] = epi(A_bf16[M,512] @ BT_bf16[N,512]^T + bias)
// MODE 0: C (bf16) = silu(acc+bias)   MODE 1: C (f32) = acc+bias+add
// ---------------------------------------------------------------------------
template <int N, int MODE>
__global__ __launch_bounds__(256) void k_gemm(
    const unsigned short* __restrict__ A, const unsigned short* __restrict__ BT,
    const float* __restrict__ bias, const float* __restrict__ add,
    void* __restrict__ Cv)
{
  __shared__ unsigned short As[128 * 40];
  __shared__ unsigned short Bs[128 * 40];
  int t = threadIdx.x;
  int w = t >> 6, l = t & 63, l15 = l & 15, lg = l >> 4;
  int wm = w >> 1, wn = w & 1;
  int row0 = blockIdx.y * 128, col0 = blockIdx.x * 128;
  f32x4 acc[4][4] = {};
  for (int k0 = 0; k0 < 512; k0 += 32) {
    __syncthreads();
    #pragma unroll
    for (int rep = 0; rep < 2; ++rep) {
      int idx = t + rep * 256;
      int row = idx >> 2, c = idx & 3;
      uint4 av = *reinterpret_cast<const uint4*>(A + (size_t)(row0 + row) * 512 + k0 + c * 8);
      *reinterpret_cast<uint4*>(&As[row * 40 + c * 8]) = av;
      uint4 bv = *reinterpret_cast<const uint4*>(BT + (size_t)(col0 + row) * 512 + k0 + c * 8);
      *reinterpret_cast<uint4*>(&Bs[row * 40 + c * 8]) = bv;
    }
    __syncthreads();
    bf16x8 af[4], bfr[4];
    #pragma unroll
    for (int mf = 0; mf < 4; ++mf)
      af[mf] = *reinterpret_cast<const bf16x8*>(&As[(wm * 64 + mf * 16 + l15) * 40 + lg * 8]);
    #pragma unroll
    for (int nf = 0; nf < 4; ++nf)
      bfr[nf] = *reinterpret_cast<const bf16x8*>(&Bs[(wn * 64 + nf * 16 + l15) * 40 + lg * 8]);
    #pragma unroll
    for (int mf = 0; mf < 4; ++mf)
      #pragma unroll
      for (int nf = 0; nf < 4; ++nf)
        acc[mf][nf] = __builtin_amdgcn_mfma_f32_16x16x32_bf16(af[mf], bfr[nf], acc[mf][nf], 0, 0, 0);
  }
  #pragma unroll
  for (int mf = 0; mf < 4; ++mf)
    #pragma unroll
    for (int nf = 0; nf < 4; ++nf)
      #pragma unroll
      for (int r = 0; r < 4; ++r) {
        int row = row0 + wm * 64 + mf * 16 + lg * 4 + r;
        int col = col0 + wn * 64 + nf * 16 + l15;
        float c = acc[mf][nf][r] + bias[col];
        if (MODE == 0) {
          c = c / (1.f + expf(-c));
          ((unsigned short*)Cv)[(size_t)row * N + col] = f2b(c);
        } else {
          ((float*)Cv)[(size_t)row * N + col] = c + add[(size_t)row * N + col];
        }
      }
}

// ---------------------------------------------------------------------------
// Kernel 4: RoPE + gates for q,k only -> (B*H, L, 64) bf16
// ---------------------------------------------------------------------------
__global__ __launch_bounds__(256) void k_rope(
    const unsigned short* __restrict__ uvqk, const float* __restrict__ pos,
    const float* __restrict__ qg, const float* __restrict__ kg,
    unsigned short* __restrict__ q_r, unsigned short* __restrict__ k_r)
{
  int p = blockIdx.x;
  int b = p >> 10, l = p & 1023;
  int t = threadIdx.x;
  int hd = t >> 5, dp = t & 31;
  const unsigned short* base = uvqk + (size_t)p * 2048;
  float ps = pos[p];
  float infq = exp2f(-(float)dp * (13.28771238f / 32.f));   // 10000^(-2dp/64)
  float ang = ps * infq;
  float c = cosf(ang), sn = sinf(ang);
  unsigned qp = *reinterpret_cast<const unsigned*>(base + 1024 + hd * 64 + 2 * dp);
  unsigned kp = *reinterpret_cast<const unsigned*>(base + 1536 + hd * 64 + 2 * dp);
  float qe = b2f((unsigned short)(qp & 0xffff)), qo = b2f((unsigned short)(qp >> 16));
  float ke = b2f((unsigned short)(kp & 0xffff)), ko = b2f((unsigned short)(kp >> 16));
  float gq = qg[p * 8 + hd], gk = kg[p * 8 + hd];
  size_t ob = ((size_t)(b * 8 + hd) * 1024 + l) * 64;
  q_r[ob + dp]      = f2b((qe * c - qo * sn) * gq);
  q_r[ob + 32 + dp] = f2b((qe * sn + qo * c) * gq);
  k_r[ob + dp]      = f2b((ke * c - ko * sn) * gk);
  k_r[ob + 32 + dp] = f2b((ke * sn + ko * c) * gk);
}

// ---------------------------------------------------------------------------
// k_vt: build V^T [bh][d][l] bf16 from uvqk (gate folded in)
// ---------------------------------------------------------------------------
__global__ __launch_bounds__(256) void k_vt(
    const unsigned short* __restrict__ uvqk, const float* __restrict__ vg,
    unsigned short* __restrict__ v_t)
{
  int lt = blockIdx.x, bh = blockIdx.y;
  int b = bh >> 3, h = bh & 7;
  __shared__ unsigned short tile[64 * 72];
  int t = threadIdx.x;
  {
    int r = t >> 2, c = (t & 3) * 16;
    int p = b * 1024 + lt * 64 + r;
    const unsigned short* src = uvqk + (size_t)p * 2048 + 512 + h * 64 + c;
    float g = vg[p * 8 + h];
    uint4 a = *reinterpret_cast<const uint4*>(src);
    uint4 b4 = *reinterpret_cast<const uint4*>(src + 8);
    unsigned short ua[16];
    *reinterpret_cast<uint4*>(&ua[0]) = a;
    *reinterpret_cast<uint4*>(&ua[8]) = b4;
    unsigned short o[16];
    #pragma unroll
    for (int e = 0; e < 16; ++e) o[e] = f2b(b2f(ua[e]) * g);
    *reinterpret_cast<uint4*>(&tile[r * 72 + c]) = *reinterpret_cast<const uint4*>(&o[0]);
    *reinterpret_cast<uint4*>(&tile[r * 72 + c + 8]) = *reinterpret_cast<const uint4*>(&o[8]);
  }
  __syncthreads();
  {
    int d = t >> 2, j = (t & 3) * 16;
    unsigned short o[16];
    #pragma unroll
    for (int e = 0; e < 16; ++e) o[e] = tile[(j + e) * 72 + d];
    unsigned short* dst = v_t + (size_t)bh * 65536 + (size_t)d * 1024 + lt * 64 + j;
    *reinterpret_cast<uint4*>(dst) = *reinterpret_cast<const uint4*>(&o[0]);
    *reinterpret_cast<uint4*>(dst + 8) = *reinterpret_cast<const uint4*>(&o[8]);
  }
}

// ---------------------------------------------------------------------------
// Kernel 5: attention via MFMA. Grid (16, 64): block = one i-tile (descending
// work order). 4 waves; rb2 fragment loads; V^T staged vectorized.
// ---------------------------------------------------------------------------
__global__ __launch_bounds__(256) void k_attn(
    const unsigned short* __restrict__ q_bf, const unsigned short* __restrict__ k_bf,
    const unsigned short* __restrict__ v_t,
    const int* __restrict__ type_seq, const unsigned short* __restrict__ rb2,
    const float* __restrict__ tpr, const float* __restrict__ head_scale,
    BTab tb, unsigned short* __restrict__ ctx)
{
  int it = 15 - blockIdx.x;
  int bh = blockIdx.y;
  int b = bh >> 3, h = bh & 7;
  int t = threadIdx.x;
  int w = t >> 6, l15 = t & 15, lg = (t >> 4) & 3;
  __shared__ unsigned short Qs[64 * 72];
  __shared__ unsigned short Ks[64 * 72];
  __shared__ unsigned short Vts[64 * 72];
  __shared__ unsigned short Ps[64 * 72];
  __shared__ float tabs4[25];
  __shared__ int tis[64], tjs[64];
  size_t hb = (size_t)bh * 65536;
  if (t < 25) tabs4[t] = 4.f * (tb.prior[t] + 0.25f * tanhf(tpr[h * 25 + t]));
  float hs = head_scale[h];
  int i0 = it << 6;
  {
    int row = t >> 2, c4 = (t & 3) * 16;
    const uint4* src = reinterpret_cast<const uint4*>(q_bf + hb + (size_t)(i0 + row) * 64 + c4);
    uint4 a = src[0], b4 = src[1];
    *reinterpret_cast<uint4*>(&Qs[row * 72 + c4]) = a;
    *reinterpret_cast<uint4*>(&Qs[row * 72 + c4 + 8]) = b4;
    if (t < 64) tis[t] = type_seq[b * 1024 + i0 + t];
  }
  f32x4 Dacc[4] = {};
  const unsigned short* rbbase = rb2 + ((size_t)(b * 136 + it * (it + 1) / 2)) * 4096 + t * 16;

  for (int jt = 0; jt <= it; ++jt) {
    int j0 = jt << 6;
    __syncthreads();
    {
      int row = t >> 2, c = (t & 3) * 16;
      const uint4* src = reinterpret_cast<const uint4*>(k_bf + hb + (size_t)(j0 + row) * 64 + c);
      uint4 a = src[0], b4 = src[1];
      *reinterpret_cast<uint4*>(&Ks[row * 72 + c]) = a;
      *reinterpret_cast<uint4*>(&Ks[row * 72 + c + 8]) = b4;
      const uint4* vsrc = reinterpret_cast<const uint4*>(v_t + hb + (size_t)row * 1024 + j0 + c);
      uint4 va = vsrc[0], vb = vsrc[1];
      *reinterpret_cast<uint4*>(&Vts[row * 72 + c]) = va;
      *reinterpret_cast<uint4*>(&Vts[row * 72 + c + 8]) = vb;
      if (t < 64) tjs[t] = type_seq[b * 1024 + j0 + t];
    }
    uint4 rb0 = *reinterpret_cast<const uint4*>(rbbase + (size_t)jt * 4096);
    uint4 rb1 = *reinterpret_cast<const uint4*>(rbbase + (size_t)jt * 4096 + 8);
    __syncthreads();

    // ---- QK^T ----
    bf16x8 qf0 = *reinterpret_cast<const bf16x8*>(&Qs[(w * 16 + l15) * 72 + lg * 8]);
    bf16x8 qf1 = *reinterpret_cast<const bf16x8*>(&Qs[(w * 16 + l15) * 72 + 32 + lg * 8]);
    f32x4 S[4] = {};
    #pragma unroll
    for (int nf = 0; nf < 4; ++nf) {
      bf16x8 kf0 = *reinterpret_cast<const bf16x8*>(&Ks[(nf * 16 + l15) * 72 + lg * 8]);
      bf16x8 kf1 = *reinterpret_cast<const bf16x8*>(&Ks[(nf * 16 + l15) * 72 + 32 + lg * 8]);
      S[nf] = __builtin_amdgcn_mfma_f32_16x16x32_bf16(qf0, kf0, S[nf], 0, 0, 0);
      S[nf] = __builtin_amdgcn_mfma_f32_16x16x32_bf16(qf1, kf1, S[nf], 0, 0, 0);
    }

    // ---- epilogue: bias + mask + silu -> Ps (bf16) ----
    unsigned short rba[16];
    *reinterpret_cast<uint4*>(&rba[0]) = rb0;
    *reinterpret_cast<uint4*>(&rba[8]) = rb1;
    bool diag = (jt == it);
    #pragma unroll
    for (int nf = 0; nf < 4; ++nf) {
      int jl = nf * 16 + l15;
      int tj = tjs[jl];
      #pragma unroll
      for (int r = 0; r < 4; ++r) {
        int il = w * 16 + lg * 4 + r;
        int ti = tis[il];
        float p = 0.f;
        bool ok = (ti != 0) && (tj != 0);
        if (diag) ok = ok && (jl <= il);
        if (ok) {
          float lgt = S[nf][r] * hs + b2f(rba[nf * 4 + r]) + tabs4[ti * 5 + tj];
          p = lgt / (1.f + expf(-lgt));
        }
        Ps[il * 72 + jl] = f2b(p);
      }
    }
    __syncthreads();

    // ---- PV ----
    bf16x8 pf0 = *reinterpret_cast<const bf16x8*>(&Ps[(w * 16 + l15) * 72 + lg * 8]);
    bf16x8 pf1 = *reinterpret_cast<const bf16x8*>(&Ps[(w * 16 + l15) * 72 + 32 + lg * 8]);
    #pragma unroll
    for (int nf = 0; nf < 4; ++nf) {
      bf16x8 vf0 = *reinterpret_cast<const bf16x8*>(&Vts[(nf * 16 + l15) * 72 + lg * 8]);
      bf16x8 vf1 = *reinterpret_cast<const bf16x8*>(&Vts[(nf * 16 + l15) * 72 + 32 + lg * 8]);
      Dacc[nf] = __builtin_amdgcn_mfma_f32_16x16x32_bf16(pf0, vf0, Dacc[nf], 0, 0, 0);
      Dacc[nf] = __builtin_amdgcn_mfma_f32_16x16x32_bf16(pf1, vf1, Dacc[nf], 0, 0, 0);
    }
  }
  #pragma unroll
  for (int nf = 0; nf < 4; ++nf)
    #pragma unroll
    for (int r = 0; r < 4; ++r) {
      int gi = i0 + w * 16 + lg * 4 + r;
      ctx[hb + (size_t)gi * 64 + nf * 16 + l15] = f2b(Dacc[nf][r]);
    }
}

// ---------------------------------------------------------------------------
// Kernel 6: LayerNorm(ctx_bf16) * u -> cw (bf16)
// ---------------------------------------------------------------------------
__global__ __launch_bounds__(256) void k_ln(
    const unsigned short* __restrict__ ctx, const unsigned short* __restrict__ uvqk,
    const float* __restrict__ ln_g, const float* __restrict__ ln_b,
    unsigned short* __restrict__ cw)
{
  int p = blockIdx.x; int b = p >> 10, l = p & 1023;
  int t = threadIdx.x;
  __shared__ float red[256];
  int d0 = 2 * t;
  int hh = d0 >> 6, dh = d0 & 63;
  unsigned cv = *reinterpret_cast<const unsigned*>(ctx + (((size_t)(b * 8 + hh)) * 1024 + l) * 64 + dh);
  float v0 = b2f((unsigned short)(cv & 0xffff)), v1 = b2f((unsigned short)(cv >> 16));
  red[t] = v0 + v1;
  __syncthreads();
  for (int o = 128; o; o >>= 1) { if (t < o) red[t] += red[t + o]; __syncthreads(); }
  float mu = red[0] * (1.f / 512.f);
  __syncthreads();
  float e0 = v0 - mu, e1 = v1 - mu;
  red[t] = e0 * e0 + e1 * e1;
  __syncthreads();
  for (int o = 128; o; o >>= 1) { if (t < o) red[t] += red[t + o]; __syncthreads(); }
  float rs = rsqrtf(red[0] * (1.f / 512.f) + 1e-5f);
  unsigned uv = *reinterpret_cast<const unsigned*>(uvqk + (size_t)p * 2048 + d0);
  float u0 = b2f((unsigned short)(uv & 0xffff)), u1 = b2f((unsigned short)(uv >> 16));
  float2 g = *reinterpret_cast<const float2*>(ln_g + d0);
  float2 bt = *reinterpret_cast<const float2*>(ln_b + d0);
  unsigned short o0 = f2b((e0 * rs * g.x + bt.x) * u0);
  unsigned short o1 = f2b((e1 * rs * g.y + bt.y) * u1);
  unsigned ov = ((unsigned)o1 << 16) | o0;
  *reinterpret_cast<unsigned*>(cw + (size_t)p * 512 + d0) = ov;
}

// ---------------------------------------------------------------------------
extern "C" void kernel_launch(void* const* d_in, const int* in_sizes, int n_in,
                              void* d_out, int out_size, void* d_ws, size_t ws_size,
                              hipStream_t stream)
{
  const float* x        = (const float*)d_in[0];
  const int*   type_seq = (const int*)d_in[1];
  const int*   seq_time = (const int*)d_in[2];
  const float* emb      = (const float*)d_in[3];
  const float* gW1 = (const float*)d_in[4];
  const float* gb1 = (const float*)d_in[5];
  const float* gW2 = (const float*)d_in[6];
  const float* gb2 = (const float*)d_in[7];
  const float* fW1 = (const float*)d_in[8];
  const float* fb1 = (const float*)d_in[9];
  const float* fW2 = (const float*)d_in[10];
  const float* fb2 = (const float*)d_in[11];
  const float* bW1 = (const float*)d_in[12];
  const float* bb1 = (const float*)d_in[13];
  const float* bW2 = (const float*)d_in[14];
  const float* bb2 = (const float*)d_in[15];
  const float* lW1 = (const float*)d_in[16];
  const float* lb1 = (const float*)d_in[17];
  const float* lW2 = (const float*)d_in[18];
  const float* lb2 = (const float*)d_in[19];
  const float* tpr = (const float*)d_in[20];
  const float* tbw = (const float*)d_in[21];
  const float* proj_w = (const float*)d_in[22];
  const float* proj_b = (const float*)d_in[23];
  const float* out_w  = (const float*)d_in[24];
  const float* out_b  = (const float*)d_in[25];
  const float* ln_g   = (const float*)d_in[26];
  const float* ln_b   = (const float*)d_in[27];
  const float* head_scale = (const float*)d_in[28];

  // workspace layout (byte-based)
  char* W = (char*)d_ws;
  float* x_new = (float*)W;                  W += (size_t)4194304 * 4;
  unsigned short* uvqk = (unsigned short*)W; W += (size_t)16777216 * 2;
  unsigned short* ctx  = (unsigned short*)W; W += (size_t)4194304 * 2;
  unsigned short* q_bf = (unsigned short*)W; W += (size_t)4194304 * 2;
  unsigned short* k_bf = (unsigned short*)W; W += (size_t)4194304 * 2;
  unsigned short* v_t  = (unsigned short*)W; W += (size_t)4194304 * 2;
  unsigned short* cw_bf = (unsigned short*)W; W += (size_t)4194304 * 2;
  unsigned short* xbf = (unsigned short*)W;  W += (size_t)4194304 * 2;
  unsigned short* pwT = (unsigned short*)W;  W += (size_t)1048576 * 2;
  unsigned short* owT = (unsigned short*)W;  W += (size_t)262144 * 2;
  unsigned short* rb2 = (unsigned short*)W;  W += (size_t)(8 * 136 * 4096) * 2;
  float* qg = (float*)W;   W += (size_t)65536 * 4;
  float* kg = (float*)W;   W += (size_t)65536 * 4;
  float* vg = (float*)W;   W += (size_t)65536 * 4;
  float* rl = (float*)W;   W += (size_t)8192 * 4;
  float* pos_ = (float*)W; W += (size_t)8192 * 4;

  BTab tb;
  {
    double step = log(86400.0 * 90.0) / 62.0;
    float vals[63];
    for (int i2 = 0; i2 < 63; ++i2) {
      double lp = exp(step * (double)i2);
      if (lp < 1.0) lp = 1.0;
      vals[i2] = (float)floor(lp);
    }
    int nb = 0; float prev = -1.f;
    for (int i2 = 0; i2 < 63; ++i2) if (vals[i2] != prev) { tb.bnd[nb++] = vals[i2]; prev = vals[i2]; }
    tb.nb = nb;
    for (int i2 = nb; i2 < 64; ++i2) tb.bnd[i2] = 3.0e38f;
    for (int i2 = 0; i2 < 25; ++i2) tb.prior[i2] = 0.f;
    tb.prior[1 * 5 + 1] = 0.05f;
    tb.prior[2 * 5 + 1] = 0.35f; tb.prior[2 * 5 + 2] = 0.05f;
    tb.prior[3 * 5 + 2] = 0.85f; tb.prior[3 * 5 + 1] = 0.25f; tb.prior[3 * 5 + 3] = 0.05f;
    tb.prior[4 * 5 + 3] = 1.2f;  tb.prior[4 * 5 + 2] = 0.8f;
    tb.prior[4 * 5 + 1] = 0.25f; tb.prior[4 * 5 + 4] = 0.1f;
  }

  k_conv<<<dim3(64, 16), 256, 0, stream>>>(proj_w, pwT, 512, 2048);
  k_conv<<<dim3(16, 16), 256, 0, stream>>>(out_w, owT, 512, 512);
  k_pre<<<1024, 256, 0, stream>>>(x, type_seq, seq_time, emb,
                                  gW1, gb1, gW2, gb2, fW1, fb1, fW2, fb2,
                                  bW1, bb1, bW2, bb2, lW1, lb1, lW2, lb2,
                                  x_new, xbf, qg, kg, vg, rl);
  k_scan<<<Bb, 1024, 0, stream>>>(rl, pos_);
  k_bias<<<dim3(136, Bb), 256, 0, stream>>>(seq_time, tbw, tb, rb2);
  k_gemm<2048, 0><<<dim3(16, 64), 256, 0, stream>>>(xbf, pwT, proj_b, nullptr, (void*)uvqk);
  k_rope<<<Bb * Ll, 256, 0, stream>>>(uvqk, pos_, qg, kg, q_bf, k_bf);
  k_vt<<<dim3(16, 64), 256, 0, stream>>>(uvqk, vg, v_t);
  k_attn<<<dim3(16, 64), 256, 0, stream>>>(q_bf, k_bf, v_t, type_seq, rb2,
                                           tpr, head_scale, tb, ctx);
  k_ln<<<Bb * Ll, 256, 0, stream>>>(ctx, uvqk, ln_g, ln_b, cw_bf);
  k_gemm<512, 1><<<dim3(4, 64), 256, 0, stream>>>(cw_bf, owT, out_b, x_new, d_out);
}

// Round 7
// 290.803 us; speedup vs baseline: 5.3761x; 1.1155x over previous
//
#include <hip/hip_runtime.h>
#include <cmath>

constexpr int Bb = 8, Hh = 8, Dd = 512, DHd = 64, Ll = 1024;

struct BTab { int nb; float bnd[64]; float prior[25]; };

typedef __attribute__((ext_vector_type(8))) short bf16x8;
typedef __attribute__((ext_vector_type(4))) float f32x4;

__device__ __forceinline__ float rcp_f(float x) { return __builtin_amdgcn_rcpf(x); }
__device__ __forceinline__ float silu_fast(float x) { return x * rcp_f(1.f + __expf(-x)); }
__device__ __forceinline__ float sigm_fast(float x) { return rcp_f(1.f + __expf(-x)); }
__device__ __forceinline__ float tanh_fast(float x) { return 1.f - 2.f * rcp_f(1.f + __expf(2.f * x)); }
__device__ __forceinline__ unsigned short f2b(float f) {
  unsigned u = __float_as_uint(f);
  unsigned r = (u + 0x7FFFu + ((u >> 16) & 1u)) >> 16;
  return (unsigned short)r;
}
__device__ __forceinline__ float b2f(unsigned short h) { return __uint_as_float(((unsigned)h) << 16); }

// ---------------------------------------------------------------------------
// transpose f32 [K][N] -> bf16 [N][K]
// ---------------------------------------------------------------------------
__global__ __launch_bounds__(256) void k_conv(const float* __restrict__ in,
                                              unsigned short* __restrict__ out, int K, int N)
{
  __shared__ float tile[32][33];
  int n0 = blockIdx.x * 32, k0 = blockIdx.y * 32;
  int t = threadIdx.x; int c = t & 31, r0 = t >> 5;
  #pragma unroll
  for (int rr = 0; rr < 4; ++rr) { int r = r0 + rr * 8; tile[r][c] = in[(size_t)(k0 + r) * N + n0 + c]; }
  __syncthreads();
  #pragma unroll
  for (int rr = 0; rr < 4; ++rr) { int r = r0 + rr * 8; out[(size_t)(n0 + r) * K + k0 + c] = f2b(tile[c][r]); }
}

// ---------------------------------------------------------------------------
// Kernel 1: per-position feature MLPs, gates, rope-lambda, x update.
// ---------------------------------------------------------------------------
__global__ __launch_bounds__(256) void k_pre(
    const float* __restrict__ x, const int* __restrict__ type_seq, const int* __restrict__ seq_time,
    const float* __restrict__ emb,
    const float* __restrict__ gW1, const float* __restrict__ gb1,
    const float* __restrict__ gW2, const float* __restrict__ gb2,
    const float* __restrict__ fW1, const float* __restrict__ fb1,
    const float* __restrict__ fW2, const float* __restrict__ fb2,
    const float* __restrict__ bW1, const float* __restrict__ bb1,
    const float* __restrict__ bW2, const float* __restrict__ bb2,
    const float* __restrict__ lW1, const float* __restrict__ lb1,
    const float* __restrict__ lW2, const float* __restrict__ lb2,
    float* __restrict__ x_new, unsigned short* __restrict__ x_new_bf,
    float* __restrict__ qg, float* __restrict__ kg,
    float* __restrict__ vg, float* __restrict__ rl)
{
  int p0 = blockIdx.x * 8;
  int t = threadIdx.x;
  __shared__ float feat[8][17];
  __shared__ float hbuf[8][6][32];
  __shared__ float mfs[8];
  int q = t >> 5, u = t & 31;
  int ty = type_seq[p0 + q];
  float mf = (ty != 0) ? 1.f : 0.f;
  if (u < 16) {
    feat[q][u] = emb[ty * 16 + u];
  } else if (u == 16) {
    int p = p0 + q, l = p & (Ll - 1);
    float dtf = 0.f;
    if (l > 0) { int dd = seq_time[p] - seq_time[p - 1]; if (dd < 0) dd = 0; dtf = (float)dd; }
    feat[q][16] = log1pf(dtf * mf);
  } else if (u == 17) {
    mfs[q] = mf;
  }
  __syncthreads();
  #pragma unroll
  for (int m = 0; m < 6; ++m) {
    const float *W1, *b1;
    switch (m) {
      case 0: case 1: case 2: W1 = gW1 + m * 544; b1 = gb1 + m * 32; break;
      case 3: W1 = fW1; b1 = fb1; break;
      case 4: W1 = bW1; b1 = bb1; break;
      default: W1 = lW1; b1 = lb1; break;
    }
    float a = b1[u];
    #pragma unroll
    for (int f = 0; f < 17; ++f) a += feat[q][f] * W1[f * 32 + u];
    hbuf[q][m][u] = silu_fast(a);
  }
  __syncthreads();
  if (t < 200) {
    int qq = t / 25, j = t - qq * 25;
    int p = p0 + qq; float m2 = mfs[qq];
    if (j < 24) {
      int g = j >> 3, hd = j & 7;
      float a = gb2[g * 8 + hd];
      #pragma unroll
      for (int uu = 0; uu < 32; ++uu) a += hbuf[qq][g][uu] * gW2[g * 256 + uu * 8 + hd];
      float coef = (g == 2) ? 0.25f : 0.12f;
      float gate = m2 * (1.f + coef * tanh_fast(a)) + (1.f - m2);
      float* dst = (g == 0) ? qg : (g == 1) ? kg : vg;
      dst[p * 8 + hd] = gate;
    } else {
      float a = lb2[0];
      #pragma unroll
      for (int uu = 0; uu < 32; ++uu) a += hbuf[qq][5][uu] * lW2[uu];
      rl[p] = (1.f + 0.15f * tanh_fast(a)) * m2;
    }
  }
  #pragma unroll
  for (int r = 0; r < 2; ++r) {
    int dd = t + (r << 8);
    float af[8], ab[8];
    #pragma unroll
    for (int q8 = 0; q8 < 8; ++q8) { af[q8] = 0.f; ab[q8] = 0.f; }
    for (int uu = 0; uu < 32; ++uu) {
      float wf = fW2[uu * 512 + dd], wb = bW2[uu * 512 + dd];
      #pragma unroll
      for (int q8 = 0; q8 < 8; ++q8) {
        af[q8] += hbuf[q8][3][uu] * wf;
        ab[q8] += hbuf[q8][4][uu] * wb;
      }
    }
    float fb = fb2[dd], bb = bb2[dd];
    #pragma unroll
    for (int q8 = 0; q8 < 8; ++q8) {
      int p = p0 + q8;
      float fg = sigm_fast(af[q8] + fb);
      float xn = x[(size_t)p * 512 + dd] + fg * ((ab[q8] + bb) * mfs[q8]);
      x_new[(size_t)p * 512 + dd] = xn;
      x_new_bf[(size_t)p * 512 + dd] = f2b(xn);
    }
  }
}

// ---------------------------------------------------------------------------
// Kernel 2: inclusive cumsum of rope-lambda along L (per batch row)
// ---------------------------------------------------------------------------
__global__ __launch_bounds__(1024) void k_scan(const float* __restrict__ rl, float* __restrict__ pos)
{
  int b = blockIdx.x, t = threadIdx.x;
  __shared__ float buf[1024];
  buf[t] = rl[b * 1024 + t];
  __syncthreads();
  for (int off = 1; off < 1024; off <<= 1) {
    float add = (t >= off) ? buf[t - off] : 0.f;
    __syncthreads();
    buf[t] += add;
    __syncthreads();
  }
  pos[b * 1024 + t] = buf[t];
}

// ---------------------------------------------------------------------------
// k_bias: rb2 f32 fragment table with mask+causal folded.
// rb2[(b*136 + tri(it,jt)) * 4096 + t*16 + nf*4+r] =
//   masked ? -30000 : 2*tbw[bucket(|Ti-Tj|)]
// ---------------------------------------------------------------------------
__global__ __launch_bounds__(256) void k_bias(
    const int* __restrict__ seq_time, const int* __restrict__ type_seq,
    const float* __restrict__ tbw, BTab tb, float* __restrict__ rb2)
{
  int f = blockIdx.x, b = blockIdx.y, t = threadIdx.x;
  int it = 0;
  while ((it + 1) * (it + 2) / 2 <= f) ++it;
  int jt = f - it * (it + 1) / 2;
  __shared__ float bnds[64], rv[64];
  __shared__ int Tis[64], Tjs[64], tis[64], tjs[64];
  if (t < 64) {
    bnds[t] = (t < tb.nb) ? tb.bnd[t] : 3.0e38f;
    rv[t] = 2.f * tbw[t];
    Tis[t] = seq_time[b * 1024 + it * 64 + t];
    Tjs[t] = seq_time[b * 1024 + jt * 64 + t];
    tis[t] = type_seq[b * 1024 + it * 64 + t];
    tjs[t] = type_seq[b * 1024 + jt * 64 + t];
  }
  __syncthreads();
  int w = t >> 6, lg = (t >> 4) & 3, l15 = t & 15;
  float o[16];
  #pragma unroll
  for (int nf = 0; nf < 4; ++nf) {
    int jl = nf * 16 + l15;
    int Tj = Tjs[jl], tj = tjs[jl];
    int gj = jt * 64 + jl;
    #pragma unroll
    for (int r = 0; r < 4; ++r) {
      int il = w * 16 + lg * 4 + r;
      int gi = it * 64 + il;
      bool masked = (gj > gi) || (tis[il] == 0) || (tj == 0);
      int td = Tis[il] - Tj; if (td < 0) td = -td; if (td < 1) td = 1;
      float tdf = (float)td;
      int lo = 0;
      #pragma unroll
      for (int st = 32; st; st >>= 1) if (bnds[lo + st - 1] < tdf) lo += st;
      if (lo > 63) lo = 63;
      o[nf * 4 + r] = masked ? -30000.f : rv[lo];
    }
  }
  float* dst = rb2 + ((size_t)(b * 136 + f)) * 4096 + t * 16;
  #pragma unroll
  for (int q4 = 0; q4 < 4; ++q4)
    *reinterpret_cast<float4*>(dst + q4 * 4) = *reinterpret_cast<const float4*>(&o[q4 * 4]);
}

// ---------------------------------------------------------------------------
// MFMA GEMM: C[M,N] = epi(A_bf16[M,512] @ BT_bf16[N,512]^T + bias)
// MODE 0: C (bf16) = silu(acc+bias)   MODE 1: C (f32) = acc+bias+add
// ---------------------------------------------------------------------------
template <int N, int MODE>
__global__ __launch_bounds__(256) void k_gemm(
    const unsigned short* __restrict__ A, const unsigned short* __restrict__ BT,
    const float* __restrict__ bias, const float* __restrict__ add,
    void* __restrict__ Cv)
{
  __shared__ unsigned short As[128 * 40];
  __shared__ unsigned short Bs[128 * 40];
  int t = threadIdx.x;
  int w = t >> 6, l = t & 63, l15 = l & 15, lg = l >> 4;
  int wm = w >> 1, wn = w & 1;
  int row0 = blockIdx.y * 128, col0 = blockIdx.x * 128;
  f32x4 acc[4][4] = {};
  for (int k0 = 0; k0 < 512; k0 += 32) {
    __syncthreads();
    #pragma unroll
    for (int rep = 0; rep < 2; ++rep) {
      int idx = t + rep * 256;
      int row = idx >> 2, c = idx & 3;
      uint4 av = *reinterpret_cast<const uint4*>(A + (size_t)(row0 + row) * 512 + k0 + c * 8);
      *reinterpret_cast<uint4*>(&As[row * 40 + c * 8]) = av;
      uint4 bv = *reinterpret_cast<const uint4*>(BT + (size_t)(col0 + row) * 512 + k0 + c * 8);
      *reinterpret_cast<uint4*>(&Bs[row * 40 + c * 8]) = bv;
    }
    __syncthreads();
    bf16x8 af[4], bfr[4];
    #pragma unroll
    for (int mf = 0; mf < 4; ++mf)
      af[mf] = *reinterpret_cast<const bf16x8*>(&As[(wm * 64 + mf * 16 + l15) * 40 + lg * 8]);
    #pragma unroll
    for (int nf = 0; nf < 4; ++nf)
      bfr[nf] = *reinterpret_cast<const bf16x8*>(&Bs[(wn * 64 + nf * 16 + l15) * 40 + lg * 8]);
    #pragma unroll
    for (int mf = 0; mf < 4; ++mf)
      #pragma unroll
      for (int nf = 0; nf < 4; ++nf)
        acc[mf][nf] = __builtin_amdgcn_mfma_f32_16x16x32_bf16(af[mf], bfr[nf], acc[mf][nf], 0, 0, 0);
  }
  #pragma unroll
  for (int mf = 0; mf < 4; ++mf)
    #pragma unroll
    for (int nf = 0; nf < 4; ++nf)
      #pragma unroll
      for (int r = 0; r < 4; ++r) {
        int row = row0 + wm * 64 + mf * 16 + lg * 4 + r;
        int col = col0 + wn * 64 + nf * 16 + l15;
        float c = acc[mf][nf][r] + bias[col];
        if (MODE == 0) {
          c = silu_fast(c);
          ((unsigned short*)Cv)[(size_t)row * N + col] = f2b(c);
        } else {
          ((float*)Cv)[(size_t)row * N + col] = c + add[(size_t)row * N + col];
        }
      }
}

// ---------------------------------------------------------------------------
// Kernel 4: RoPE + gates for q,k only -> (B*H, L, 64) bf16
// ---------------------------------------------------------------------------
__global__ __launch_bounds__(256) void k_rope(
    const unsigned short* __restrict__ uvqk, const float* __restrict__ pos,
    const float* __restrict__ qg, const float* __restrict__ kg,
    unsigned short* __restrict__ q_r, unsigned short* __restrict__ k_r)
{
  int p = blockIdx.x;
  int b = p >> 10, l = p & 1023;
  int t = threadIdx.x;
  int hd = t >> 5, dp = t & 31;
  const unsigned short* base = uvqk + (size_t)p * 2048;
  float ps = pos[p];
  float infq = exp2f(-(float)dp * (13.28771238f / 32.f));   // 10000^(-2dp/64)
  float ang = ps * infq;
  float c = cosf(ang), sn = sinf(ang);
  unsigned qp = *reinterpret_cast<const unsigned*>(base + 1024 + hd * 64 + 2 * dp);
  unsigned kp = *reinterpret_cast<const unsigned*>(base + 1536 + hd * 64 + 2 * dp);
  float qe = b2f((unsigned short)(qp & 0xffff)), qo = b2f((unsigned short)(qp >> 16));
  float ke = b2f((unsigned short)(kp & 0xffff)), ko = b2f((unsigned short)(kp >> 16));
  float gq = qg[p * 8 + hd], gk = kg[p * 8 + hd];
  size_t ob = ((size_t)(b * 8 + hd) * 1024 + l) * 64;
  q_r[ob + dp]      = f2b((qe * c - qo * sn) * gq);
  q_r[ob + 32 + dp] = f2b((qe * sn + qo * c) * gq);
  k_r[ob + dp]      = f2b((ke * c - ko * sn) * gk);
  k_r[ob + 32 + dp] = f2b((ke * sn + ko * c) * gk);
}

// ---------------------------------------------------------------------------
// k_vt: build V^T [bh][d][l] bf16 from uvqk (gate folded in)
// ---------------------------------------------------------------------------
__global__ __launch_bounds__(256) void k_vt(
    const unsigned short* __restrict__ uvqk, const float* __restrict__ vg,
    unsigned short* __restrict__ v_t)
{
  int lt = blockIdx.x, bh = blockIdx.y;
  int b = bh >> 3, h = bh & 7;
  __shared__ unsigned short tile[64 * 72];
  int t = threadIdx.x;
  {
    int r = t >> 2, c = (t & 3) * 16;
    int p = b * 1024 + lt * 64 + r;
    const unsigned short* src = uvqk + (size_t)p * 2048 + 512 + h * 64 + c;
    float g = vg[p * 8 + h];
    uint4 a = *reinterpret_cast<const uint4*>(src);
    uint4 b4 = *reinterpret_cast<const uint4*>(src + 8);
    unsigned short ua[16];
    *reinterpret_cast<uint4*>(&ua[0]) = a;
    *reinterpret_cast<uint4*>(&ua[8]) = b4;
    unsigned short o[16];
    #pragma unroll
    for (int e = 0; e < 16; ++e) o[e] = f2b(b2f(ua[e]) * g);
    *reinterpret_cast<uint4*>(&tile[r * 72 + c]) = *reinterpret_cast<const uint4*>(&o[0]);
    *reinterpret_cast<uint4*>(&tile[r * 72 + c + 8]) = *reinterpret_cast<const uint4*>(&o[8]);
  }
  __syncthreads();
  {
    int d = t >> 2, j = (t & 3) * 16;
    unsigned short o[16];
    #pragma unroll
    for (int e = 0; e < 16; ++e) o[e] = tile[(j + e) * 72 + d];
    unsigned short* dst = v_t + (size_t)bh * 65536 + (size_t)d * 1024 + lt * 64 + j;
    *reinterpret_cast<uint4*>(dst) = *reinterpret_cast<const uint4*>(&o[0]);
    *reinterpret_cast<uint4*>(dst + 8) = *reinterpret_cast<const uint4*>(&o[8]);
  }
}

// ---------------------------------------------------------------------------
// Kernel 5: attention via MFMA. Grid (32, 64): block = (i-tile, j-half).
// px = blockIdx.x: it = 15-(px>>1), half = px&1. Partial ctx per half (bf16),
// summed in k_ln. Mask/causal/rab folded in rb2 (f32); pair via f32 LDS.
// ---------------------------------------------------------------------------
__global__ __launch_bounds__(256) void k_attn(
    const unsigned short* __restrict__ q_bf, const unsigned short* __restrict__ k_bf,
    const unsigned short* __restrict__ v_t,
    const int* __restrict__ type_seq, const float* __restrict__ rb2,
    const float* __restrict__ tpr, const float* __restrict__ head_scale,
    BTab tb, unsigned short* __restrict__ ctx0, unsigned short* __restrict__ ctx1)
{
  int px = blockIdx.x;
  int it = 15 - (px >> 1), half = px & 1;
  int bh = blockIdx.y;
  int b = bh >> 3, h = bh & 7;
  int nj = it + 1;
  int jt0 = half ? (nj + 1) / 2 : 0;
  int jt1 = half ? nj : (nj + 1) / 2;
  int t = threadIdx.x;
  int w = t >> 6, l15 = t & 15, lg = (t >> 4) & 3;
  __shared__ unsigned short Qs[64 * 72];
  __shared__ unsigned short Ks[64 * 72];
  __shared__ unsigned short Vts[64 * 72];
  __shared__ unsigned short Ps[64 * 72];
  __shared__ float tabs4[25];
  __shared__ int tis[64], tjs[64];
  size_t hb = (size_t)bh * 65536;
  if (t < 25) tabs4[t] = 4.f * (tb.prior[t] + 0.25f * tanh_fast(tpr[h * 25 + t]));
  float hs = head_scale[h];
  int i0 = it << 6;
  {
    int row = t >> 2, c4 = (t & 3) * 16;
    const uint4* src = reinterpret_cast<const uint4*>(q_bf + hb + (size_t)(i0 + row) * 64 + c4);
    uint4 a = src[0], b4 = src[1];
    *reinterpret_cast<uint4*>(&Qs[row * 72 + c4]) = a;
    *reinterpret_cast<uint4*>(&Qs[row * 72 + c4 + 8]) = b4;
    if (t < 64) tis[t] = type_seq[b * 1024 + i0 + t];
  }
  __syncthreads();
  int ti5[4];
  #pragma unroll
  for (int r = 0; r < 4; ++r) ti5[r] = tis[w * 16 + lg * 4 + r] * 5;

  f32x4 Dacc[4] = {};
  const float* rbbase = rb2 + ((size_t)(b * 136 + it * (it + 1) / 2)) * 4096 + t * 16;

  for (int jt = jt0; jt < jt1; ++jt) {
    int j0 = jt << 6;
    __syncthreads();
    // rb fragment (f32, 16 values) — issue early to overlap with staging
    const float* rbp = rbbase + (size_t)jt * 4096;
    float4 rq0 = *reinterpret_cast<const float4*>(rbp);
    float4 rq1 = *reinterpret_cast<const float4*>(rbp + 4);
    float4 rq2 = *reinterpret_cast<const float4*>(rbp + 8);
    float4 rq3 = *reinterpret_cast<const float4*>(rbp + 12);
    {
      int row = t >> 2, c = (t & 3) * 16;
      const uint4* src = reinterpret_cast<const uint4*>(k_bf + hb + (size_t)(j0 + row) * 64 + c);
      uint4 a = src[0], b4 = src[1];
      *reinterpret_cast<uint4*>(&Ks[row * 72 + c]) = a;
      *reinterpret_cast<uint4*>(&Ks[row * 72 + c + 8]) = b4;
      const uint4* vsrc = reinterpret_cast<const uint4*>(v_t + hb + (size_t)row * 1024 + j0 + c);
      uint4 va = vsrc[0], vb = vsrc[1];
      *reinterpret_cast<uint4*>(&Vts[row * 72 + c]) = va;
      *reinterpret_cast<uint4*>(&Vts[row * 72 + c + 8]) = vb;
      if (t < 64) tjs[t] = type_seq[b * 1024 + j0 + t];
    }
    __syncthreads();

    // ---- QK^T ----
    bf16x8 qf0 = *reinterpret_cast<const bf16x8*>(&Qs[(w * 16 + l15) * 72 + lg * 8]);
    bf16x8 qf1 = *reinterpret_cast<const bf16x8*>(&Qs[(w * 16 + l15) * 72 + 32 + lg * 8]);
    f32x4 S[4] = {};
    #pragma unroll
    for (int nf = 0; nf < 4; ++nf) {
      bf16x8 kf0 = *reinterpret_cast<const bf16x8*>(&Ks[(nf * 16 + l15) * 72 + lg * 8]);
      bf16x8 kf1 = *reinterpret_cast<const bf16x8*>(&Ks[(nf * 16 + l15) * 72 + 32 + lg * 8]);
      S[nf] = __builtin_amdgcn_mfma_f32_16x16x32_bf16(qf0, kf0, S[nf], 0, 0, 0);
      S[nf] = __builtin_amdgcn_mfma_f32_16x16x32_bf16(qf1, kf1, S[nf], 0, 0, 0);
    }

    // ---- epilogue: logit = S*hs + rb + pair; fast silu -> Ps ----
    float rba[16];
    *reinterpret_cast<float4*>(&rba[0])  = rq0;
    *reinterpret_cast<float4*>(&rba[4])  = rq1;
    *reinterpret_cast<float4*>(&rba[8])  = rq2;
    *reinterpret_cast<float4*>(&rba[12]) = rq3;
    int tjv[4];
    #pragma unroll
    for (int nf = 0; nf < 4; ++nf) tjv[nf] = tjs[nf * 16 + l15];
    #pragma unroll
    for (int nf = 0; nf < 4; ++nf) {
      int jl = nf * 16 + l15;
      #pragma unroll
      for (int r = 0; r < 4; ++r) {
        int il = w * 16 + lg * 4 + r;
        float lgt = fmaf(S[nf][r], hs, rba[nf * 4 + r]) + tabs4[ti5[r] + tjv[nf]];
        Ps[il * 72 + jl] = f2b(silu_fast(lgt));
      }
    }
    __syncthreads();

    // ---- PV ----
    bf16x8 pf0 = *reinterpret_cast<const bf16x8*>(&Ps[(w * 16 + l15) * 72 + lg * 8]);
    bf16x8 pf1 = *reinterpret_cast<const bf16x8*>(&Ps[(w * 16 + l15) * 72 + 32 + lg * 8]);
    #pragma unroll
    for (int nf = 0; nf < 4; ++nf) {
      bf16x8 vf0 = *reinterpret_cast<const bf16x8*>(&Vts[(nf * 16 + l15) * 72 + lg * 8]);
      bf16x8 vf1 = *reinterpret_cast<const bf16x8*>(&Vts[(nf * 16 + l15) * 72 + 32 + lg * 8]);
      Dacc[nf] = __builtin_amdgcn_mfma_f32_16x16x32_bf16(pf0, vf0, Dacc[nf], 0, 0, 0);
      Dacc[nf] = __builtin_amdgcn_mfma_f32_16x16x32_bf16(pf1, vf1, Dacc[nf], 0, 0, 0);
    }
  }
  unsigned short* ctxp = half ? ctx1 : ctx0;
  #pragma unroll
  for (int nf = 0; nf < 4; ++nf)
    #pragma unroll
    for (int r = 0; r < 4; ++r) {
      int gi = i0 + w * 16 + lg * 4 + r;
      ctxp[hb + (size_t)gi * 64 + nf * 16 + l15] = f2b(Dacc[nf][r]);
    }
}

// ---------------------------------------------------------------------------
// Kernel 6: LayerNorm(ctx0+ctx1) * u -> cw (bf16)
// ---------------------------------------------------------------------------
__global__ __launch_bounds__(256) void k_ln(
    const unsigned short* __restrict__ ctx0, const unsigned short* __restrict__ ctx1,
    const unsigned short* __restrict__ uvqk,
    const float* __restrict__ ln_g, const float* __restrict__ ln_b,
    unsigned short* __restrict__ cw)
{
  int p = blockIdx.x; int b = p >> 10, l = p & 1023;
  int t = threadIdx.x;
  __shared__ float red[256];
  int d0 = 2 * t;
  int hh = d0 >> 6, dh = d0 & 63;
  size_t cidx = (((size_t)(b * 8 + hh)) * 1024 + l) * 64 + dh;
  unsigned cv0 = *reinterpret_cast<const unsigned*>(ctx0 + cidx);
  unsigned cv1 = *reinterpret_cast<const unsigned*>(ctx1 + cidx);
  float v0 = b2f((unsigned short)(cv0 & 0xffff)) + b2f((unsigned short)(cv1 & 0xffff));
  float v1 = b2f((unsigned short)(cv0 >> 16)) + b2f((unsigned short)(cv1 >> 16));
  red[t] = v0 + v1;
  __syncthreads();
  for (int o = 128; o; o >>= 1) { if (t < o) red[t] += red[t + o]; __syncthreads(); }
  float mu = red[0] * (1.f / 512.f);
  __syncthreads();
  float e0 = v0 - mu, e1 = v1 - mu;
  red[t] = e0 * e0 + e1 * e1;
  __syncthreads();
  for (int o = 128; o; o >>= 1) { if (t < o) red[t] += red[t + o]; __syncthreads(); }
  float rs = rsqrtf(red[0] * (1.f / 512.f) + 1e-5f);
  unsigned uv = *reinterpret_cast<const unsigned*>(uvqk + (size_t)p * 2048 + d0);
  float u0 = b2f((unsigned short)(uv & 0xffff)), u1 = b2f((unsigned short)(uv >> 16));
  float2 g = *reinterpret_cast<const float2*>(ln_g + d0);
  float2 bt = *reinterpret_cast<const float2*>(ln_b + d0);
  unsigned short o0 = f2b((e0 * rs * g.x + bt.x) * u0);
  unsigned short o1 = f2b((e1 * rs * g.y + bt.y) * u1);
  unsigned ov = ((unsigned)o1 << 16) | o0;
  *reinterpret_cast<unsigned*>(cw + (size_t)p * 512 + d0) = ov;
}

// ---------------------------------------------------------------------------
extern "C" void kernel_launch(void* const* d_in, const int* in_sizes, int n_in,
                              void* d_out, int out_size, void* d_ws, size_t ws_size,
                              hipStream_t stream)
{
  const float* x        = (const float*)d_in[0];
  const int*   type_seq = (const int*)d_in[1];
  const int*   seq_time = (const int*)d_in[2];
  const float* emb      = (const float*)d_in[3];
  const float* gW1 = (const float*)d_in[4];
  const float* gb1 = (const float*)d_in[5];
  const float* gW2 = (const float*)d_in[6];
  const float* gb2 = (const float*)d_in[7];
  const float* fW1 = (const float*)d_in[8];
  const float* fb1 = (const float*)d_in[9];
  const float* fW2 = (const float*)d_in[10];
  const float* fb2 = (const float*)d_in[11];
  const float* bW1 = (const float*)d_in[12];
  const float* bb1 = (const float*)d_in[13];
  const float* bW2 = (const float*)d_in[14];
  const float* bb2 = (const float*)d_in[15];
  const float* lW1 = (const float*)d_in[16];
  const float* lb1 = (const float*)d_in[17];
  const float* lW2 = (const float*)d_in[18];
  const float* lb2 = (const float*)d_in[19];
  const float* tpr = (const float*)d_in[20];
  const float* tbw = (const float*)d_in[21];
  const float* proj_w = (const float*)d_in[22];
  const float* proj_b = (const float*)d_in[23];
  const float* out_w  = (const float*)d_in[24];
  const float* out_b  = (const float*)d_in[25];
  const float* ln_g   = (const float*)d_in[26];
  const float* ln_b   = (const float*)d_in[27];
  const float* head_scale = (const float*)d_in[28];

  // workspace layout (byte-based)
  char* W = (char*)d_ws;
  float* x_new = (float*)W;                  W += (size_t)4194304 * 4;
  unsigned short* uvqk = (unsigned short*)W; W += (size_t)16777216 * 2;
  unsigned short* ctx0 = (unsigned short*)W; W += (size_t)4194304 * 2;
  unsigned short* ctx1 = (unsigned short*)W; W += (size_t)4194304 * 2;
  unsigned short* q_bf = (unsigned short*)W; W += (size_t)4194304 * 2;
  unsigned short* k_bf = (unsigned short*)W; W += (size_t)4194304 * 2;
  unsigned short* v_t  = (unsigned short*)W; W += (size_t)4194304 * 2;
  unsigned short* cw_bf = (unsigned short*)W; W += (size_t)4194304 * 2;
  unsigned short* xbf = (unsigned short*)W;  W += (size_t)4194304 * 2;
  unsigned short* pwT = (unsigned short*)W;  W += (size_t)1048576 * 2;
  unsigned short* owT = (unsigned short*)W;  W += (size_t)262144 * 2;
  float* rb2 = (float*)W;                    W += (size_t)(8 * 136 * 4096) * 4;
  float* qg = (float*)W;   W += (size_t)65536 * 4;
  float* kg = (float*)W;   W += (size_t)65536 * 4;
  float* vg = (float*)W;   W += (size_t)65536 * 4;
  float* rl = (float*)W;   W += (size_t)8192 * 4;
  float* pos_ = (float*)W; W += (size_t)8192 * 4;

  BTab tb;
  {
    double step = log(86400.0 * 90.0) / 62.0;
    float vals[63];
    for (int i2 = 0; i2 < 63; ++i2) {
      double lp = exp(step * (double)i2);
      if (lp < 1.0) lp = 1.0;
      vals[i2] = (float)floor(lp);
    }
    int nb = 0; float prev = -1.f;
    for (int i2 = 0; i2 < 63; ++i2) if (vals[i2] != prev) { tb.bnd[nb++] = vals[i2]; prev = vals[i2]; }
    tb.nb = nb;
    for (int i2 = nb; i2 < 64; ++i2) tb.bnd[i2] = 3.0e38f;
    for (int i2 = 0; i2 < 25; ++i2) tb.prior[i2] = 0.f;
    tb.prior[1 * 5 + 1] = 0.05f;
    tb.prior[2 * 5 + 1] = 0.35f; tb.prior[2 * 5 + 2] = 0.05f;
    tb.prior[3 * 5 + 2] = 0.85f; tb.prior[3 * 5 + 1] = 0.25f; tb.prior[3 * 5 + 3] = 0.05f;
    tb.prior[4 * 5 + 3] = 1.2f;  tb.prior[4 * 5 + 2] = 0.8f;
    tb.prior[4 * 5 + 1] = 0.25f; tb.prior[4 * 5 + 4] = 0.1f;
  }

  k_conv<<<dim3(64, 16), 256, 0, stream>>>(proj_w, pwT, 512, 2048);
  k_conv<<<dim3(16, 16), 256, 0, stream>>>(out_w, owT, 512, 512);
  k_pre<<<1024, 256, 0, stream>>>(x, type_seq, seq_time, emb,
                                  gW1, gb1, gW2, gb2, fW1, fb1, fW2, fb2,
                                  bW1, bb1, bW2, bb2, lW1, lb1, lW2, lb2,
                                  x_new, xbf, qg, kg, vg, rl);
  k_scan<<<Bb, 1024, 0, stream>>>(rl, pos_);
  k_bias<<<dim3(136, Bb), 256, 0, stream>>>(seq_time, type_seq, tbw, tb, rb2);
  k_gemm<2048, 0><<<dim3(16, 64), 256, 0, stream>>>(xbf, pwT, proj_b, nullptr, (void*)uvqk);
  k_rope<<<Bb * Ll, 256, 0, stream>>>(uvqk, pos_, qg, kg, q_bf, k_bf);
  k_vt<<<dim3(16, 64), 256, 0, stream>>>(uvqk, vg, v_t);
  k_attn<<<dim3(32, 64), 256, 0, stream>>>(q_bf, k_bf, v_t, type_seq, rb2,
                                           tpr, head_scale, tb, ctx0, ctx1);
  k_ln<<<Bb * Ll, 256, 0, stream>>>(ctx0, ctx1, uvqk, ln_g, ln_b, cw_bf);
  k_gemm<512, 1><<<dim3(4, 64), 256, 0, stream>>>(cw_bf, owT, out_b, x_new, d_out);
}

// Round 8
// 269.022 us; speedup vs baseline: 5.8114x; 1.0810x over previous
//
#include <hip/hip_runtime.h>
#include <cmath>

constexpr int Bb = 8, Hh = 8, Dd = 512, DHd = 64, Ll = 1024;

struct BTab { int nb; float bnd[64]; float prior[25]; };

typedef __attribute__((ext_vector_type(8))) short bf16x8;
typedef __attribute__((ext_vector_type(4))) float f32x4;

__device__ __forceinline__ float rcp_f(float x) { return __builtin_amdgcn_rcpf(x); }
__device__ __forceinline__ float silu_fast(float x) { return x * rcp_f(1.f + __expf(-x)); }
__device__ __forceinline__ float sigm_fast(float x) { return rcp_f(1.f + __expf(-x)); }
__device__ __forceinline__ float tanh_fast(float x) { return 1.f - 2.f * rcp_f(1.f + __expf(2.f * x)); }
__device__ __forceinline__ unsigned short f2b(float f) {
  unsigned u = __float_as_uint(f);
  unsigned r = (u + 0x7FFFu + ((u >> 16) & 1u)) >> 16;
  return (unsigned short)r;
}
__device__ __forceinline__ float b2f(unsigned short h) { return __uint_as_float(((unsigned)h) << 16); }

// ---------------------------------------------------------------------------
// transpose f32 [K][N] -> bf16 [N][K]
// ---------------------------------------------------------------------------
__global__ __launch_bounds__(256) void k_conv(const float* __restrict__ in,
                                              unsigned short* __restrict__ out, int K, int N)
{
  __shared__ float tile[32][33];
  int n0 = blockIdx.x * 32, k0 = blockIdx.y * 32;
  int t = threadIdx.x; int c = t & 31, r0 = t >> 5;
  #pragma unroll
  for (int rr = 0; rr < 4; ++rr) { int r = r0 + rr * 8; tile[r][c] = in[(size_t)(k0 + r) * N + n0 + c]; }
  __syncthreads();
  #pragma unroll
  for (int rr = 0; rr < 4; ++rr) { int r = r0 + rr * 8; out[(size_t)(n0 + r) * K + k0 + c] = f2b(tile[c][r]); }
}

// ---------------------------------------------------------------------------
// Kernel 1: per-position feature MLPs, gates, rope-lambda, x update.
// hbufT[m][u][q8] layout -> phase-3 h reads are vector b128 broadcasts.
// ---------------------------------------------------------------------------
__global__ __launch_bounds__(256) void k_pre(
    const float* __restrict__ x, const int* __restrict__ type_seq, const int* __restrict__ seq_time,
    const float* __restrict__ emb,
    const float* __restrict__ gW1, const float* __restrict__ gb1,
    const float* __restrict__ gW2, const float* __restrict__ gb2,
    const float* __restrict__ fW1, const float* __restrict__ fb1,
    const float* __restrict__ fW2, const float* __restrict__ fb2,
    const float* __restrict__ bW1, const float* __restrict__ bb1,
    const float* __restrict__ bW2, const float* __restrict__ bb2,
    const float* __restrict__ lW1, const float* __restrict__ lb1,
    const float* __restrict__ lW2, const float* __restrict__ lb2,
    float* __restrict__ x_new, unsigned short* __restrict__ x_new_bf,
    float* __restrict__ qg, float* __restrict__ kg,
    float* __restrict__ vg, float* __restrict__ rl)
{
  int p0 = blockIdx.x * 8;
  int t = threadIdx.x;
  __shared__ float feat[8][17];
  __shared__ float hbufT[6][32][8];   // [m][u][q8]
  __shared__ float mfs[8];
  int q = t >> 5, u = t & 31;
  int ty = type_seq[p0 + q];
  float mf = (ty != 0) ? 1.f : 0.f;
  if (u < 16) {
    feat[q][u] = emb[ty * 16 + u];
  } else if (u == 16) {
    int p = p0 + q, l = p & (Ll - 1);
    float dtf = 0.f;
    if (l > 0) { int dd = seq_time[p] - seq_time[p - 1]; if (dd < 0) dd = 0; dtf = (float)dd; }
    feat[q][16] = log1pf(dtf * mf);
  } else if (u == 17) {
    mfs[q] = mf;
  }
  __syncthreads();
  #pragma unroll
  for (int m = 0; m < 6; ++m) {
    const float *W1, *b1;
    switch (m) {
      case 0: case 1: case 2: W1 = gW1 + m * 544; b1 = gb1 + m * 32; break;
      case 3: W1 = fW1; b1 = fb1; break;
      case 4: W1 = bW1; b1 = bb1; break;
      default: W1 = lW1; b1 = lb1; break;
    }
    float a = b1[u];
    #pragma unroll
    for (int f = 0; f < 17; ++f) a += feat[q][f] * W1[f * 32 + u];
    hbufT[m][u][q] = silu_fast(a);
  }
  __syncthreads();
  if (t < 200) {
    int qq = t / 25, j = t - qq * 25;
    int p = p0 + qq; float m2 = mfs[qq];
    if (j < 24) {
      int g = j >> 3, hd = j & 7;
      float a = gb2[g * 8 + hd];
      #pragma unroll
      for (int uu = 0; uu < 32; ++uu) a += hbufT[g][uu][qq] * gW2[g * 256 + uu * 8 + hd];
      float coef = (g == 2) ? 0.25f : 0.12f;
      float gate = m2 * (1.f + coef * tanh_fast(a)) + (1.f - m2);
      float* dst = (g == 0) ? qg : (g == 1) ? kg : vg;
      dst[p * 8 + hd] = gate;
    } else {
      float a = lb2[0];
      #pragma unroll
      for (int uu = 0; uu < 32; ++uu) a += hbufT[5][uu][qq] * lW2[uu];
      rl[p] = (1.f + 0.15f * tanh_fast(a)) * m2;
    }
  }
  // phase-3: 2 dd per thread, 8 positions each
  int dd0 = t, dd1 = t + 256;
  float af[2][8], ab[2][8];
  #pragma unroll
  for (int r = 0; r < 2; ++r)
    #pragma unroll
    for (int q8 = 0; q8 < 8; ++q8) { af[r][q8] = 0.f; ab[r][q8] = 0.f; }
  #pragma unroll 4
  for (int uu = 0; uu < 32; ++uu) {
    float h3r[8], h4r[8];
    *reinterpret_cast<float4*>(&h3r[0]) = *reinterpret_cast<const float4*>(&hbufT[3][uu][0]);
    *reinterpret_cast<float4*>(&h3r[4]) = *reinterpret_cast<const float4*>(&hbufT[3][uu][4]);
    *reinterpret_cast<float4*>(&h4r[0]) = *reinterpret_cast<const float4*>(&hbufT[4][uu][0]);
    *reinterpret_cast<float4*>(&h4r[4]) = *reinterpret_cast<const float4*>(&hbufT[4][uu][4]);
    float wf0 = fW2[uu * 512 + dd0], wb0 = bW2[uu * 512 + dd0];
    float wf1 = fW2[uu * 512 + dd1], wb1 = bW2[uu * 512 + dd1];
    #pragma unroll
    for (int q8 = 0; q8 < 8; ++q8) {
      af[0][q8] = fmaf(h3r[q8], wf0, af[0][q8]);
      af[1][q8] = fmaf(h3r[q8], wf1, af[1][q8]);
      ab[0][q8] = fmaf(h4r[q8], wb0, ab[0][q8]);
      ab[1][q8] = fmaf(h4r[q8], wb1, ab[1][q8]);
    }
  }
  #pragma unroll
  for (int r = 0; r < 2; ++r) {
    int dd = r ? dd1 : dd0;
    float fb = fb2[dd], bb = bb2[dd];
    #pragma unroll
    for (int q8 = 0; q8 < 8; ++q8) {
      int p = p0 + q8;
      float fg = sigm_fast(af[r][q8] + fb);
      float xn = x[(size_t)p * 512 + dd] + fg * ((ab[r][q8] + bb) * mfs[q8]);
      x_new[(size_t)p * 512 + dd] = xn;
      x_new_bf[(size_t)p * 512 + dd] = f2b(xn);
    }
  }
}

// ---------------------------------------------------------------------------
// Kernel 2: inclusive cumsum of rope-lambda along L (per batch row)
// ---------------------------------------------------------------------------
__global__ __launch_bounds__(1024) void k_scan(const float* __restrict__ rl, float* __restrict__ pos)
{
  int b = blockIdx.x, t = threadIdx.x;
  __shared__ float buf[1024];
  buf[t] = rl[b * 1024 + t];
  __syncthreads();
  for (int off = 1; off < 1024; off <<= 1) {
    float add = (t >= off) ? buf[t - off] : 0.f;
    __syncthreads();
    buf[t] += add;
    __syncthreads();
  }
  pos[b * 1024 + t] = buf[t];
}

// ---------------------------------------------------------------------------
// k_bias: rb2 bf16 fragment table with mask+causal+2*rab folded.
// ---------------------------------------------------------------------------
__global__ __launch_bounds__(256) void k_bias(
    const int* __restrict__ seq_time, const int* __restrict__ type_seq,
    const float* __restrict__ tbw, BTab tb, unsigned short* __restrict__ rb2)
{
  int f = blockIdx.x, b = blockIdx.y, t = threadIdx.x;
  int it = 0;
  while ((it + 1) * (it + 2) / 2 <= f) ++it;
  int jt = f - it * (it + 1) / 2;
  __shared__ float bnds[64], rv[64];
  __shared__ int Tis[64], Tjs[64], tis[64], tjs[64];
  if (t < 64) {
    bnds[t] = (t < tb.nb) ? tb.bnd[t] : 3.0e38f;
    rv[t] = 2.f * tbw[t];
    Tis[t] = seq_time[b * 1024 + it * 64 + t];
    Tjs[t] = seq_time[b * 1024 + jt * 64 + t];
    tis[t] = type_seq[b * 1024 + it * 64 + t];
    tjs[t] = type_seq[b * 1024 + jt * 64 + t];
  }
  __syncthreads();
  int w = t >> 6, lg = (t >> 4) & 3, l15 = t & 15;
  unsigned short o[16];
  #pragma unroll
  for (int nf = 0; nf < 4; ++nf) {
    int jl = nf * 16 + l15;
    int Tj = Tjs[jl], tj = tjs[jl];
    int gj = jt * 64 + jl;
    #pragma unroll
    for (int r = 0; r < 4; ++r) {
      int il = w * 16 + lg * 4 + r;
      int gi = it * 64 + il;
      bool masked = (gj > gi) || (tis[il] == 0) || (tj == 0);
      int td = Tis[il] - Tj; if (td < 0) td = -td; if (td < 1) td = 1;
      float tdf = (float)td;
      int lo = 0;
      #pragma unroll
      for (int st = 32; st; st >>= 1) if (bnds[lo + st - 1] < tdf) lo += st;
      if (lo > 63) lo = 63;
      o[nf * 4 + r] = f2b(masked ? -30000.f : rv[lo]);
    }
  }
  unsigned short* dst = rb2 + ((size_t)(b * 136 + f)) * 4096 + t * 16;
  *reinterpret_cast<uint4*>(dst) = *reinterpret_cast<const uint4*>(&o[0]);
  *reinterpret_cast<uint4*>(dst + 8) = *reinterpret_cast<const uint4*>(&o[8]);
}

// ---------------------------------------------------------------------------
// MFMA GEMM with register prefetch of next K-step.
// MODE 0: C (bf16) = silu(acc+bias)   MODE 1: C (f32) = acc+bias+add
// ---------------------------------------------------------------------------
template <int N, int MODE>
__global__ __launch_bounds__(256) void k_gemm(
    const unsigned short* __restrict__ A, const unsigned short* __restrict__ BT,
    const float* __restrict__ bias, const float* __restrict__ add,
    void* __restrict__ Cv)
{
  __shared__ unsigned short As[128 * 40];
  __shared__ unsigned short Bs[128 * 40];
  int t = threadIdx.x;
  int w = t >> 6, l = t & 63, l15 = l & 15, lg = l >> 4;
  int wm = w >> 1, wn = w & 1;
  int row0 = blockIdx.y * 128, col0 = blockIdx.x * 128;
  int lrow = t >> 1, lc = (t & 1) * 16;   // 256 threads: row 0..127, 16-elem chunk
  const unsigned short* Ap = A + (size_t)(row0 + lrow) * 512 + lc;
  const unsigned short* Bp = BT + (size_t)(col0 + lrow) * 512 + lc;
  uint4 av0, av1, bv0, bv1;
  av0 = *reinterpret_cast<const uint4*>(Ap);
  av1 = *reinterpret_cast<const uint4*>(Ap + 8);
  bv0 = *reinterpret_cast<const uint4*>(Bp);
  bv1 = *reinterpret_cast<const uint4*>(Bp + 8);
  f32x4 acc[4][4] = {};
  for (int k0 = 0; k0 < 512; k0 += 32) {
    __syncthreads();
    *reinterpret_cast<uint4*>(&As[lrow * 40 + lc]) = av0;
    *reinterpret_cast<uint4*>(&As[lrow * 40 + lc + 8]) = av1;
    *reinterpret_cast<uint4*>(&Bs[lrow * 40 + lc]) = bv0;
    *reinterpret_cast<uint4*>(&Bs[lrow * 40 + lc + 8]) = bv1;
    if (k0 + 32 < 512) {
      av0 = *reinterpret_cast<const uint4*>(Ap + k0 + 32);
      av1 = *reinterpret_cast<const uint4*>(Ap + k0 + 40);
      bv0 = *reinterpret_cast<const uint4*>(Bp + k0 + 32);
      bv1 = *reinterpret_cast<const uint4*>(Bp + k0 + 40);
    }
    __syncthreads();
    bf16x8 af[4], bfr[4];
    #pragma unroll
    for (int mf = 0; mf < 4; ++mf)
      af[mf] = *reinterpret_cast<const bf16x8*>(&As[(wm * 64 + mf * 16 + l15) * 40 + lg * 8]);
    #pragma unroll
    for (int nf = 0; nf < 4; ++nf)
      bfr[nf] = *reinterpret_cast<const bf16x8*>(&Bs[(wn * 64 + nf * 16 + l15) * 40 + lg * 8]);
    #pragma unroll
    for (int mf = 0; mf < 4; ++mf)
      #pragma unroll
      for (int nf = 0; nf < 4; ++nf)
        acc[mf][nf] = __builtin_amdgcn_mfma_f32_16x16x32_bf16(af[mf], bfr[nf], acc[mf][nf], 0, 0, 0);
  }
  #pragma unroll
  for (int mf = 0; mf < 4; ++mf)
    #pragma unroll
    for (int nf = 0; nf < 4; ++nf)
      #pragma unroll
      for (int r = 0; r < 4; ++r) {
        int row = row0 + wm * 64 + mf * 16 + lg * 4 + r;
        int col = col0 + wn * 64 + nf * 16 + l15;
        float c = acc[mf][nf][r] + bias[col];
        if (MODE == 0) {
          c = silu_fast(c);
          ((unsigned short*)Cv)[(size_t)row * N + col] = f2b(c);
        } else {
          ((float*)Cv)[(size_t)row * N + col] = c + add[(size_t)row * N + col];
        }
      }
}

// ---------------------------------------------------------------------------
// Kernel 4: RoPE + gates for q,k only -> (B*H, L, 64) bf16 (HW sin/cos)
// ---------------------------------------------------------------------------
__global__ __launch_bounds__(256) void k_rope(
    const unsigned short* __restrict__ uvqk, const float* __restrict__ pos,
    const float* __restrict__ qg, const float* __restrict__ kg,
    unsigned short* __restrict__ q_r, unsigned short* __restrict__ k_r)
{
  int p = blockIdx.x;
  int b = p >> 10, l = p & 1023;
  int t = threadIdx.x;
  int hd = t >> 5, dp = t & 31;
  const unsigned short* base = uvqk + (size_t)p * 2048;
  float ps = pos[p];
  float infq = exp2f(-(float)dp * (13.28771238f / 32.f));   // 10000^(-2dp/64)
  float ang = ps * infq;
  float c = __cosf(ang), sn = __sinf(ang);
  unsigned qp = *reinterpret_cast<const unsigned*>(base + 1024 + hd * 64 + 2 * dp);
  unsigned kp = *reinterpret_cast<const unsigned*>(base + 1536 + hd * 64 + 2 * dp);
  float qe = b2f((unsigned short)(qp & 0xffff)), qo = b2f((unsigned short)(qp >> 16));
  float ke = b2f((unsigned short)(kp & 0xffff)), ko = b2f((unsigned short)(kp >> 16));
  float gq = qg[p * 8 + hd], gk = kg[p * 8 + hd];
  size_t ob = ((size_t)(b * 8 + hd) * 1024 + l) * 64;
  q_r[ob + dp]      = f2b((qe * c - qo * sn) * gq);
  q_r[ob + 32 + dp] = f2b((qe * sn + qo * c) * gq);
  k_r[ob + dp]      = f2b((ke * c - ko * sn) * gk);
  k_r[ob + 32 + dp] = f2b((ke * sn + ko * c) * gk);
}

// ---------------------------------------------------------------------------
// k_vt: build V^T [bh][d][l] bf16 from uvqk (gate folded in)
// ---------------------------------------------------------------------------
__global__ __launch_bounds__(256) void k_vt(
    const unsigned short* __restrict__ uvqk, const float* __restrict__ vg,
    unsigned short* __restrict__ v_t)
{
  int lt = blockIdx.x, bh = blockIdx.y;
  int b = bh >> 3, h = bh & 7;
  __shared__ unsigned short tile[64 * 72];
  int t = threadIdx.x;
  {
    int r = t >> 2, c = (t & 3) * 16;
    int p = b * 1024 + lt * 64 + r;
    const unsigned short* src = uvqk + (size_t)p * 2048 + 512 + h * 64 + c;
    float g = vg[p * 8 + h];
    uint4 a = *reinterpret_cast<const uint4*>(src);
    uint4 b4 = *reinterpret_cast<const uint4*>(src + 8);
    unsigned short ua[16];
    *reinterpret_cast<uint4*>(&ua[0]) = a;
    *reinterpret_cast<uint4*>(&ua[8]) = b4;
    unsigned short o[16];
    #pragma unroll
    for (int e = 0; e < 16; ++e) o[e] = f2b(b2f(ua[e]) * g);
    *reinterpret_cast<uint4*>(&tile[r * 72 + c]) = *reinterpret_cast<const uint4*>(&o[0]);
    *reinterpret_cast<uint4*>(&tile[r * 72 + c + 8]) = *reinterpret_cast<const uint4*>(&o[8]);
  }
  __syncthreads();
  {
    int d = t >> 2, j = (t & 3) * 16;
    unsigned short o[16];
    #pragma unroll
    for (int e = 0; e < 16; ++e) o[e] = tile[(j + e) * 72 + d];
    unsigned short* dst = v_t + (size_t)bh * 65536 + (size_t)d * 1024 + lt * 64 + j;
    *reinterpret_cast<uint4*>(dst) = *reinterpret_cast<const uint4*>(&o[0]);
    *reinterpret_cast<uint4*>(dst + 8) = *reinterpret_cast<const uint4*>(&o[8]);
  }
}

// ---------------------------------------------------------------------------
// Kernel 5: attention via MFMA, register-prefetched staging (T14).
// Grid (32, 64): it = 15-(px>>1), half = px&1; partial ctx summed in k_ln.
// ---------------------------------------------------------------------------
__global__ __launch_bounds__(256) void k_attn(
    const unsigned short* __restrict__ q_bf, const unsigned short* __restrict__ k_bf,
    const unsigned short* __restrict__ v_t,
    const int* __restrict__ type_seq, const unsigned short* __restrict__ rb2,
    const float* __restrict__ tpr, const float* __restrict__ head_scale,
    BTab tb, unsigned short* __restrict__ ctx0, unsigned short* __restrict__ ctx1)
{
  int px = blockIdx.x;
  int it = 15 - (px >> 1), half = px & 1;
  int bh = blockIdx.y;
  int b = bh >> 3, h = bh & 7;
  int nj = it + 1;
  int jt0 = half ? (nj + 1) / 2 : 0;
  int jt1 = half ? nj : (nj + 1) / 2;
  int t = threadIdx.x;
  int w = t >> 6, l15 = t & 15, lg = (t >> 4) & 3;
  __shared__ unsigned short Qs[64 * 72];
  __shared__ unsigned short Ks[64 * 72];
  __shared__ unsigned short Vts[64 * 72];
  __shared__ unsigned short Ps[64 * 72];
  __shared__ float tabs4[25];
  __shared__ int tis[64], tjs[64];
  size_t hb = (size_t)bh * 65536;
  if (t < 25) tabs4[t] = 4.f * (tb.prior[t] + 0.25f * tanh_fast(tpr[h * 25 + t]));
  float hs = head_scale[h];
  int i0 = it << 6;
  {
    int row = t >> 2, c4 = (t & 3) * 16;
    const uint4* src = reinterpret_cast<const uint4*>(q_bf + hb + (size_t)(i0 + row) * 64 + c4);
    uint4 a = src[0], b4 = src[1];
    *reinterpret_cast<uint4*>(&Qs[row * 72 + c4]) = a;
    *reinterpret_cast<uint4*>(&Qs[row * 72 + c4 + 8]) = b4;
    if (t < 64) tis[t] = type_seq[b * 1024 + i0 + t];
  }
  __syncthreads();
  int ti5[4];
  #pragma unroll
  for (int r = 0; r < 4; ++r) ti5[r] = tis[w * 16 + lg * 4 + r] * 5;

  f32x4 Dacc[4] = {};
  const unsigned short* rbbase = rb2 + ((size_t)(b * 136 + it * (it + 1) / 2)) * 4096 + t * 16;
  int srow = t >> 2, sc = (t & 3) * 16;   // staging coords

  uint4 ck0, ck1, cv0, cv1, crb0, crb1;
  int ctj = 0;
  if (jt0 < jt1) {   // prefetch first tile
    int j0 = jt0 << 6;
    const uint4* ksrc = reinterpret_cast<const uint4*>(k_bf + hb + (size_t)(j0 + srow) * 64 + sc);
    ck0 = ksrc[0]; ck1 = ksrc[1];
    const uint4* vsrc = reinterpret_cast<const uint4*>(v_t + hb + (size_t)srow * 1024 + j0 + sc);
    cv0 = vsrc[0]; cv1 = vsrc[1];
    const unsigned short* rbp = rbbase + (size_t)jt0 * 4096;
    crb0 = *reinterpret_cast<const uint4*>(rbp);
    crb1 = *reinterpret_cast<const uint4*>(rbp + 8);
    if (t < 64) ctj = type_seq[b * 1024 + j0 + t];
  }

  for (int jt = jt0; jt < jt1; ++jt) {
    // unpack rb (before prefetch overwrites regs)
    float rba[16];
    {
      const unsigned short* rs = reinterpret_cast<const unsigned short*>(&crb0);
      #pragma unroll
      for (int e = 0; e < 8; ++e) rba[e] = b2f(rs[e]);
      rs = reinterpret_cast<const unsigned short*>(&crb1);
      #pragma unroll
      for (int e = 0; e < 8; ++e) rba[8 + e] = b2f(rs[e]);
    }
    __syncthreads();   // prior iter QK/PV reads of Ks/Vts done
    *reinterpret_cast<uint4*>(&Ks[srow * 72 + sc]) = ck0;
    *reinterpret_cast<uint4*>(&Ks[srow * 72 + sc + 8]) = ck1;
    *reinterpret_cast<uint4*>(&Vts[srow * 72 + sc]) = cv0;
    *reinterpret_cast<uint4*>(&Vts[srow * 72 + sc + 8]) = cv1;
    if (t < 64) tjs[t] = ctj;
    // prefetch next tile (latency hides under QK+epi+PV)
    if (jt + 1 < jt1) {
      int j0n = (jt + 1) << 6;
      const uint4* ksrc = reinterpret_cast<const uint4*>(k_bf + hb + (size_t)(j0n + srow) * 64 + sc);
      ck0 = ksrc[0]; ck1 = ksrc[1];
      const uint4* vsrc = reinterpret_cast<const uint4*>(v_t + hb + (size_t)srow * 1024 + j0n + sc);
      cv0 = vsrc[0]; cv1 = vsrc[1];
      const unsigned short* rbp = rbbase + (size_t)(jt + 1) * 4096;
      crb0 = *reinterpret_cast<const uint4*>(rbp);
      crb1 = *reinterpret_cast<const uint4*>(rbp + 8);
      if (t < 64) ctj = type_seq[b * 1024 + j0n + t];
    }
    __syncthreads();

    // ---- QK^T ----
    bf16x8 qf0 = *reinterpret_cast<const bf16x8*>(&Qs[(w * 16 + l15) * 72 + lg * 8]);
    bf16x8 qf1 = *reinterpret_cast<const bf16x8*>(&Qs[(w * 16 + l15) * 72 + 32 + lg * 8]);
    f32x4 S[4] = {};
    #pragma unroll
    for (int nf = 0; nf < 4; ++nf) {
      bf16x8 kf0 = *reinterpret_cast<const bf16x8*>(&Ks[(nf * 16 + l15) * 72 + lg * 8]);
      bf16x8 kf1 = *reinterpret_cast<const bf16x8*>(&Ks[(nf * 16 + l15) * 72 + 32 + lg * 8]);
      S[nf] = __builtin_amdgcn_mfma_f32_16x16x32_bf16(qf0, kf0, S[nf], 0, 0, 0);
      S[nf] = __builtin_amdgcn_mfma_f32_16x16x32_bf16(qf1, kf1, S[nf], 0, 0, 0);
    }

    // ---- epilogue: logit = S*hs + rb + pair; fast silu -> Ps ----
    int tjv[4];
    #pragma unroll
    for (int nf = 0; nf < 4; ++nf) tjv[nf] = tjs[nf * 16 + l15];
    #pragma unroll
    for (int nf = 0; nf < 4; ++nf) {
      int jl = nf * 16 + l15;
      #pragma unroll
      for (int r = 0; r < 4; ++r) {
        int il = w * 16 + lg * 4 + r;
        float lgt = fmaf(S[nf][r], hs, rba[nf * 4 + r]) + tabs4[ti5[r] + tjv[nf]];
        Ps[il * 72 + jl] = f2b(silu_fast(lgt));
      }
    }
    __syncthreads();

    // ---- PV ----
    bf16x8 pf0 = *reinterpret_cast<const bf16x8*>(&Ps[(w * 16 + l15) * 72 + lg * 8]);
    bf16x8 pf1 = *reinterpret_cast<const bf16x8*>(&Ps[(w * 16 + l15) * 72 + 32 + lg * 8]);
    #pragma unroll
    for (int nf = 0; nf < 4; ++nf) {
      bf16x8 vf0 = *reinterpret_cast<const bf16x8*>(&Vts[(nf * 16 + l15) * 72 + lg * 8]);
      bf16x8 vf1 = *reinterpret_cast<const bf16x8*>(&Vts[(nf * 16 + l15) * 72 + 32 + lg * 8]);
      Dacc[nf] = __builtin_amdgcn_mfma_f32_16x16x32_bf16(pf0, vf0, Dacc[nf], 0, 0, 0);
      Dacc[nf] = __builtin_amdgcn_mfma_f32_16x16x32_bf16(pf1, vf1, Dacc[nf], 0, 0, 0);
    }
  }
  unsigned short* ctxp = half ? ctx1 : ctx0;
  #pragma unroll
  for (int nf = 0; nf < 4; ++nf)
    #pragma unroll
    for (int r = 0; r < 4; ++r) {
      int gi = i0 + w * 16 + lg * 4 + r;
      ctxp[hb + (size_t)gi * 64 + nf * 16 + l15] = f2b(Dacc[nf][r]);
    }
}

// ---------------------------------------------------------------------------
// Kernel 6: LayerNorm(ctx0+ctx1) * u -> cw (bf16)
// ---------------------------------------------------------------------------
__global__ __launch_bounds__(256) void k_ln(
    const unsigned short* __restrict__ ctx0, const unsigned short* __restrict__ ctx1,
    const unsigned short* __restrict__ uvqk,
    const float* __restrict__ ln_g, const float* __restrict__ ln_b,
    unsigned short* __restrict__ cw)
{
  int p = blockIdx.x; int b = p >> 10, l = p & 1023;
  int t = threadIdx.x;
  __shared__ float red[256];
  int d0 = 2 * t;
  int hh = d0 >> 6, dh = d0 & 63;
  size_t cidx = (((size_t)(b * 8 + hh)) * 1024 + l) * 64 + dh;
  unsigned cv0 = *reinterpret_cast<const unsigned*>(ctx0 + cidx);
  unsigned cv1 = *reinterpret_cast<const unsigned*>(ctx1 + cidx);
  float v0 = b2f((unsigned short)(cv0 & 0xffff)) + b2f((unsigned short)(cv1 & 0xffff));
  float v1 = b2f((unsigned short)(cv0 >> 16)) + b2f((unsigned short)(cv1 >> 16));
  red[t] = v0 + v1;
  __syncthreads();
  for (int o = 128; o; o >>= 1) { if (t < o) red[t] += red[t + o]; __syncthreads(); }
  float mu = red[0] * (1.f / 512.f);
  __syncthreads();
  float e0 = v0 - mu, e1 = v1 - mu;
  red[t] = e0 * e0 + e1 * e1;
  __syncthreads();
  for (int o = 128; o; o >>= 1) { if (t < o) red[t] += red[t + o]; __syncthreads(); }
  float rs = rsqrtf(red[0] * (1.f / 512.f) + 1e-5f);
  unsigned uv = *reinterpret_cast<const unsigned*>(uvqk + (size_t)p * 2048 + d0);
  float u0 = b2f((unsigned short)(uv & 0xffff)), u1 = b2f((unsigned short)(uv >> 16));
  float2 g = *reinterpret_cast<const float2*>(ln_g + d0);
  float2 bt = *reinterpret_cast<const float2*>(ln_b + d0);
  unsigned short o0 = f2b((e0 * rs * g.x + bt.x) * u0);
  unsigned short o1 = f2b((e1 * rs * g.y + bt.y) * u1);
  unsigned ov = ((unsigned)o1 << 16) | o0;
  *reinterpret_cast<unsigned*>(cw + (size_t)p * 512 + d0) = ov;
}

// ---------------------------------------------------------------------------
extern "C" void kernel_launch(void* const* d_in, const int* in_sizes, int n_in,
                              void* d_out, int out_size, void* d_ws, size_t ws_size,
                              hipStream_t stream)
{
  const float* x        = (const float*)d_in[0];
  const int*   type_seq = (const int*)d_in[1];
  const int*   seq_time = (const int*)d_in[2];
  const float* emb      = (const float*)d_in[3];
  const float* gW1 = (const float*)d_in[4];
  const float* gb1 = (const float*)d_in[5];
  const float* gW2 = (const float*)d_in[6];
  const float* gb2 = (const float*)d_in[7];
  const float* fW1 = (const float*)d_in[8];
  const float* fb1 = (const float*)d_in[9];
  const float* fW2 = (const float*)d_in[10];
  const float* fb2 = (const float*)d_in[11];
  const float* bW1 = (const float*)d_in[12];
  const float* bb1 = (const float*)d_in[13];
  const float* bW2 = (const float*)d_in[14];
  const float* bb2 = (const float*)d_in[15];
  const float* lW1 = (const float*)d_in[16];
  const float* lb1 = (const float*)d_in[17];
  const float* lW2 = (const float*)d_in[18];
  const float* lb2 = (const float*)d_in[19];
  const float* tpr = (const float*)d_in[20];
  const float* tbw = (const float*)d_in[21];
  const float* proj_w = (const float*)d_in[22];
  const float* proj_b = (const float*)d_in[23];
  const float* out_w  = (const float*)d_in[24];
  const float* out_b  = (const float*)d_in[25];
  const float* ln_g   = (const float*)d_in[26];
  const float* ln_b   = (const float*)d_in[27];
  const float* head_scale = (const float*)d_in[28];

  // workspace layout (byte-based)
  char* W = (char*)d_ws;
  float* x_new = (float*)W;                  W += (size_t)4194304 * 4;
  unsigned short* uvqk = (unsigned short*)W; W += (size_t)16777216 * 2;
  unsigned short* ctx0 = (unsigned short*)W; W += (size_t)4194304 * 2;
  unsigned short* ctx1 = (unsigned short*)W; W += (size_t)4194304 * 2;
  unsigned short* q_bf = (unsigned short*)W; W += (size_t)4194304 * 2;
  unsigned short* k_bf = (unsigned short*)W; W += (size_t)4194304 * 2;
  unsigned short* v_t  = (unsigned short*)W; W += (size_t)4194304 * 2;
  unsigned short* cw_bf = (unsigned short*)W; W += (size_t)4194304 * 2;
  unsigned short* xbf = (unsigned short*)W;  W += (size_t)4194304 * 2;
  unsigned short* pwT = (unsigned short*)W;  W += (size_t)1048576 * 2;
  unsigned short* owT = (unsigned short*)W;  W += (size_t)262144 * 2;
  unsigned short* rb2 = (unsigned short*)W;  W += (size_t)(8 * 136 * 4096) * 2;
  float* qg = (float*)W;   W += (size_t)65536 * 4;
  float* kg = (float*)W;   W += (size_t)65536 * 4;
  float* vg = (float*)W;   W += (size_t)65536 * 4;
  float* rl = (float*)W;   W += (size_t)8192 * 4;
  float* pos_ = (float*)W; W += (size_t)8192 * 4;

  BTab tb;
  {
    double step = log(86400.0 * 90.0) / 62.0;
    float vals[63];
    for (int i2 = 0; i2 < 63; ++i2) {
      double lp = exp(step * (double)i2);
      if (lp < 1.0) lp = 1.0;
      vals[i2] = (float)floor(lp);
    }
    int nb = 0; float prev = -1.f;
    for (int i2 = 0; i2 < 63; ++i2) if (vals[i2] != prev) { tb.bnd[nb++] = vals[i2]; prev = vals[i2]; }
    tb.nb = nb;
    for (int i2 = nb; i2 < 64; ++i2) tb.bnd[i2] = 3.0e38f;
    for (int i2 = 0; i2 < 25; ++i2) tb.prior[i2] = 0.f;
    tb.prior[1 * 5 + 1] = 0.05f;
    tb.prior[2 * 5 + 1] = 0.35f; tb.prior[2 * 5 + 2] = 0.05f;
    tb.prior[3 * 5 + 2] = 0.85f; tb.prior[3 * 5 + 1] = 0.25f; tb.prior[3 * 5 + 3] = 0.05f;
    tb.prior[4 * 5 + 3] = 1.2f;  tb.prior[4 * 5 + 2] = 0.8f;
    tb.prior[4 * 5 + 1] = 0.25f; tb.prior[4 * 5 + 4] = 0.1f;
  }

  k_conv<<<dim3(64, 16), 256, 0, stream>>>(proj_w, pwT, 512, 2048);
  k_conv<<<dim3(16, 16), 256, 0, stream>>>(out_w, owT, 512, 512);
  k_pre<<<1024, 256, 0, stream>>>(x, type_seq, seq_time, emb,
                                  gW1, gb1, gW2, gb2, fW1, fb1, fW2, fb2,
                                  bW1, bb1, bW2, bb2, lW1, lb1, lW2, lb2,
                                  x_new, xbf, qg, kg, vg, rl);
  k_scan<<<Bb, 1024, 0, stream>>>(rl, pos_);
  k_bias<<<dim3(136, Bb), 256, 0, stream>>>(seq_time, type_seq, tbw, tb, rb2);
  k_gemm<2048, 0><<<dim3(16, 64), 256, 0, stream>>>(xbf, pwT, proj_b, nullptr, (void*)uvqk);
  k_rope<<<Bb * Ll, 256, 0, stream>>>(uvqk, pos_, qg, kg, q_bf, k_bf);
  k_vt<<<dim3(16, 64), 256, 0, stream>>>(uvqk, vg, v_t);
  k_attn<<<dim3(32, 64), 256, 0, stream>>>(q_bf, k_bf, v_t, type_seq, rb2,
                                           tpr, head_scale, tb, ctx0, ctx1);
  k_ln<<<Bb * Ll, 256, 0, stream>>>(ctx0, ctx1, uvqk, ln_g, ln_b, cw_bf);
  k_gemm<512, 1><<<dim3(4, 64), 256, 0, stream>>>(cw_bf, owT, out_b, x_new, d_out);
}